// Round 3
// baseline (286.839 us; speedup 1.0000x reference)
//
#include <hip/hip_runtime.h>
#include <math.h>

#define KNB 12
#define GRD 8
#define NCELL (GRD * GRD * GRD)   // 512 cells, cell edge = 0.125

// ---------------------------------------------------------------- helpers

__device__ __forceinline__ unsigned umin32(unsigned a, unsigned b) {
    unsigned r; asm("v_min_u32 %0, %1, %2" : "=v"(r) : "v"(a), "v"(b)); return r;
}
__device__ __forceinline__ unsigned umax32(unsigned a, unsigned b) {
    unsigned r; asm("v_max_u32 %0, %1, %2" : "=v"(r) : "v"(a), "v"(b)); return r;
}

// ---------------- f32 no-contract primitives (match CPU netlib rounding)
__device__ __forceinline__ float fm(float a, float b) { return __fmul_rn(a, b); }
__device__ __forceinline__ float fa(float a, float b) { return __fadd_rn(a, b); }
__device__ __forceinline__ float fs(float a, float b) { return __fsub_rn(a, b); }
__device__ __forceinline__ float fsignf(float a, float b) { return (b >= 0.0f) ? fabsf(a) : -fabsf(a); }

__device__ float slapy2_(float x, float y) {
    float xa = fabsf(x), ya = fabsf(y);
    float w = fmaxf(xa, ya), z = fminf(xa, ya);
    if (z == 0.0f) return w;
    float q = z / w;
    return fm(w, __fsqrt_rn(fa(1.0f, fm(q, q))));
}

// LAPACK >=3.10 slartg: c = |f|/d >= 0, r = sign(f)*d
__device__ void slartg_(float f, float g, float& c, float& s, float& r) {
    if (g == 0.0f) { c = 1.0f; s = 0.0f; r = f; }
    else if (f == 0.0f) { c = 0.0f; s = (g >= 0.0f) ? 1.0f : -1.0f; r = fabsf(g); }
    else {
        float d = __fsqrt_rn(fa(fm(f, f), fm(g, g)));
        c = fabsf(f) / d;
        r = (f >= 0.0f) ? d : -d;
        s = g / r;
    }
}

// netlib slaev2 (f32): eigvec of RT1 is (cs1, sn1)
__device__ void slaev2_(float a, float b, float cc,
                        float& rt1, float& rt2, float& cs1, float& sn1) {
    float sm = fa(a, cc), df = fs(a, cc), adf = fabsf(df);
    float tb = fa(b, b), ab = fabsf(tb);
    float acmx, acmn;
    if (fabsf(a) > fabsf(cc)) { acmx = a; acmn = cc; } else { acmx = cc; acmn = a; }
    float rt;
    if (adf > ab)      { float q = ab / adf; rt = fm(adf, __fsqrt_rn(fa(1.0f, fm(q, q)))); }
    else if (adf < ab) { float q = adf / ab; rt = fm(ab,  __fsqrt_rn(fa(1.0f, fm(q, q)))); }
    else               rt = fm(ab, __fsqrt_rn(2.0f));
    int sgn1;
    if (sm < 0.0f) {
        rt1 = fm(0.5f, fs(sm, rt)); sgn1 = -1;
        rt2 = fs(fm(acmx / rt1, acmn), fm(b / rt1, b));
    } else if (sm > 0.0f) {
        rt1 = fm(0.5f, fa(sm, rt)); sgn1 = 1;
        rt2 = fs(fm(acmx / rt1, acmn), fm(b / rt1, b));
    } else { rt1 = fm(0.5f, rt); rt2 = fm(-0.5f, rt); sgn1 = 1; }
    int sgn2; float cs;
    if (df >= 0.0f) { cs = fa(df, rt); sgn2 = 1; } else { cs = fs(df, rt); sgn2 = -1; }
    float acs = fabsf(cs);
    if (acs > ab) {
        float ct = -tb / cs;
        sn1 = 1.0f / __fsqrt_rn(fa(1.0f, fm(ct, ct)));
        cs1 = fm(ct, sn1);
    } else {
        if (ab == 0.0f) { cs1 = 1.0f; sn1 = 0.0f; }
        else {
            float tn = -cs / tb;
            cs1 = 1.0f / __fsqrt_rn(fa(1.0f, fm(tn, tn)));
            sn1 = fm(tn, cs1);
        }
    }
    if (sgn1 == sgn2) { float tn = cs1; cs1 = -sn1; sn1 = tn; }
}

// slasr single rotation on Z columns (j1,j2): a* = col j1, b* = col j2.
// Literal netlib expression order.
__device__ __forceinline__ void rot2col(float& a1, float& a2, float& a3,
                                        float& b1, float& b2, float& b3,
                                        float ct, float st) {
    float t;
    t = b1; b1 = fs(fm(ct, t), fm(st, a1)); a1 = fa(fm(st, t), fm(ct, a1));
    t = b2; b2 = fs(fm(ct, t), fm(st, a2)); a2 = fa(fm(st, t), fm(ct, a2));
    t = b3; b3 = fs(fm(ct, t), fm(st, a3)); a3 = fa(fm(st, t), fm(ct, a3));
}

// dynamic-index accessors over NAMED registers (cndmask selects, no memory).
// For n=3 all dynamic indices are in {1,2,3}; the QL/QR sweeps are provably
// fixed at (l,mq)=(1,3)/(3,1) and fully unrolled below -> zero LDS/scratch.
#define RD(i)    ((i) == 1 ? d1 : ((i) == 2 ? d2 : d3))
#define WRD(i,v) do { float _t = (v); if ((i) == 1) d1 = _t; else if ((i) == 2) d2 = _t; else d3 = _t; } while (0)
#define RE(i)    ((i) == 1 ? e1 : e2)
#define WRE(i,v) do { float _t = (v); if ((i) == 1) e1 = _t; else e2 = _t; } while (0)
#define SWAPC(a,b) do { float _t = (a); (a) = (b); (b) = _t; } while (0)

// Faithful f32 port of ssyevd path (ssytd2 'L' -> ssteqr 'I' -> sormtr) for a
// 3x3 symmetric-lower matrix; eigvec of smallest eigenvalue, LAPACK signs.
// Pure-register storage: identical op sequence to the LDS version (bit-equal),
// but every D/E/Z access is a VALU select instead of a ~120-cyc LDS round-trip.
__device__ void eig3_smallest_reg(float a00, float a10, float a20,
                                  float a11, float a21, float a22,
                                  float& v1o, float& v2o, float& v3o) {
    float z11 = 1.0f, z21 = 0.0f, z31 = 0.0f;
    float z12 = 0.0f, z22 = 1.0f, z32 = 0.0f;
    float z13 = 0.0f, z23 = 0.0f, z33 = 1.0f;
    float d1, d2, d3, e1, e2;
    float wc1 = 0.0f, wc2 = 0.0f, ws1 = 0.0f, ws2 = 0.0f;

    // --- ssytd2 'L' (single Householder on column 1), faithful BLAS op order
    float tau = 0.0f, v3 = 0.0f;
    d1 = a00;
    if (a20 != 0.0f) {
        float xn = fabsf(a20);                      // snrm2 length-1
        float beta = -fsignf(slapy2_(a10, xn), a10);
        tau = fs(beta, a10) / beta;
        float rinv = 1.0f / fs(a10, beta);          // sscal: recip then mul
        v3 = fm(a20, rinv);
        e1 = beta;
        // ssymv lower n=2: w = tau * A22 * (1, v3)
        float w1 = fa(fm(tau, a11), fm(tau, fm(a21, v3)));
        float w2 = fa(fm(tau, a21), fm(fm(tau, v3), a22));
        float dot = fa(w1, fm(w2, v3));
        float al = fm(fm(-0.5f, tau), dot);
        w1 = fa(w1, al);
        w2 = fa(w2, fm(al, v3));
        d2 = fs(fs(a11, w1), w1);
        e2 = fs(fs(a21, fm(v3, w1)), w2);
        d3 = fs(fs(a22, fm(v3, w2)), fm(w2, v3));
    } else {
        e1 = a10; d2 = a11; e2 = a21; d3 = a22;
    }

    // --- ssteqr 'I' (f32 constants)
    const float eps = 5.9604645e-8f;        // slamch('E') = 2^-24
    const float eps2 = 3.5527137e-15f;      // eps^2
    const float safmin = 1.17549435e-38f;   // slamch('S')
    int jtot = 0; const int nmaxit = 90;
    int l1 = 1;
    while (l1 <= 3) {
        if (l1 > 1) WRE(l1 - 1, 0.0f);
        int m;
        for (m = l1; m <= 2; ++m) {
            float tst = fabsf(RE(m));
            if (tst == 0.0f) break;
            if (tst <= fm(fm(__fsqrt_rn(fabsf(RD(m))), __fsqrt_rn(fabsf(RD(m + 1)))), eps)) {
                WRE(m, 0.0f); break;
            }
        }
        int l = l1, lend = m;
        l1 = m + 1;
        if (lend == l) continue;
        if (fabsf(RD(lend)) < fabsf(RD(l))) { int t = l; l = lend; lend = t; }
        if (lend > l) {
            // QL iteration
            for (;;) {
                int mq = lend;
                if (l != lend) {
                    for (mq = l; mq <= lend - 1; ++mq) {
                        float tst = fm(RE(mq), RE(mq));
                        if (tst <= fa(fm(fm(eps2, fabsf(RD(mq))), fabsf(RD(mq + 1))), safmin)) break;
                    }
                }
                if (mq < lend) WRE(mq, 0.0f);
                float p = RD(l);
                if (mq == l) { l += 1; if (l <= lend) continue; break; }
                if (mq == l + 1) {
                    float rt1, rt2, cc, ss;
                    if (l == 1) {
                        slaev2_(d1, e1, d2, rt1, rt2, cc, ss);
                        rot2col(z11, z21, z31, z12, z22, z32, cc, ss);
                        d1 = rt1; d2 = rt2; e1 = 0.0f;
                    } else {
                        slaev2_(d2, e2, d3, rt1, rt2, cc, ss);
                        rot2col(z12, z22, z32, z13, z23, z33, cc, ss);
                        d2 = rt1; d3 = rt2; e2 = 0.0f;
                    }
                    l += 2; if (l <= lend) continue; break;
                }
                if (jtot == nmaxit) break;
                jtot++;
                // sweep: reachable only with l==1, mq==3 (|mq-l|>=2 in 1..3)
                float g = fs(d2, p) / fm(2.0f, e1);
                float r = slapy2_(g, 1.0f);
                g = fa(fs(d3, p), e1 / fa(g, fsignf(r, g)));
                float s_ = 1.0f, c_ = 1.0f; p = 0.0f;
                {   // i = 2 (== mq-1: no E(i+1) store)
                    float f = fm(s_, e2), b = fm(c_, e2);
                    slartg_(g, f, c_, s_, r);
                    g = fs(d3, p);
                    r = fa(fm(fs(d2, g), s_), fm(fm(2.0f, c_), b));
                    p = fm(s_, r);
                    d3 = fa(g, p);
                    g = fs(fm(c_, r), b);
                    wc2 = c_; ws2 = -s_;      // QL stores -S
                }
                {   // i = 1: E(2) = r
                    float f = fm(s_, e1), b = fm(c_, e1);
                    slartg_(g, f, c_, s_, r);
                    e2 = r;
                    g = fs(d2, p);
                    r = fa(fm(fs(d1, g), s_), fm(fm(2.0f, c_), b));
                    p = fm(s_, r);
                    d2 = fa(g, p);
                    g = fs(fm(c_, r), b);
                    wc1 = c_; ws1 = -s_;
                }
                rot2col(z12, z22, z32, z13, z23, z33, wc2, ws2);   // rotcf(2,3)
                rot2col(z11, z21, z31, z12, z22, z32, wc1, ws1);   // rotcf(1,2)
                d1 = fs(d1, p); e1 = g;
            }
        } else {
            // QR iteration
            for (;;) {
                int mq = lend;
                if (l != lend) {
                    for (mq = l; mq >= lend + 1; --mq) {
                        float tst = fm(RE(mq - 1), RE(mq - 1));
                        if (tst <= fa(fm(fm(eps2, fabsf(RD(mq))), fabsf(RD(mq - 1))), safmin)) break;
                    }
                }
                if (mq > lend) WRE(mq - 1, 0.0f);
                float p = RD(l);
                if (mq == l) { l -= 1; if (l >= lend) continue; break; }
                if (mq == l - 1) {
                    float rt1, rt2, cc, ss;
                    if (l == 2) {
                        slaev2_(d1, e1, d2, rt1, rt2, cc, ss);
                        rot2col(z11, z21, z31, z12, z22, z32, cc, ss);
                        d1 = rt1; d2 = rt2; e1 = 0.0f;
                    } else {  // l == 3
                        slaev2_(d2, e2, d3, rt1, rt2, cc, ss);
                        rot2col(z12, z22, z32, z13, z23, z33, cc, ss);
                        d2 = rt1; d3 = rt2; e2 = 0.0f;
                    }
                    l -= 2; if (l >= lend) continue; break;
                }
                if (jtot == nmaxit) break;
                jtot++;
                // sweep: reachable only with l==3, mq==1
                float g = fs(d2, p) / fm(2.0f, e2);
                float r = slapy2_(g, 1.0f);
                g = fa(fs(d1, p), e2 / fa(g, fsignf(r, g)));
                float s_ = 1.0f, c_ = 1.0f; p = 0.0f;
                {   // i = 1 (== mq: no E(i-1) store)
                    float f = fm(s_, e1), b = fm(c_, e1);
                    slartg_(g, f, c_, s_, r);
                    g = fs(d1, p);
                    r = fa(fm(fs(d2, g), s_), fm(fm(2.0f, c_), b));
                    p = fm(s_, r);
                    d1 = fa(g, p);
                    g = fs(fm(c_, r), b);
                    wc1 = c_; ws1 = s_;       // QR stores +S
                }
                {   // i = 2: E(1) = r
                    float f = fm(s_, e2), b = fm(c_, e2);
                    slartg_(g, f, c_, s_, r);
                    e1 = r;
                    g = fs(d2, p);
                    r = fa(fm(fs(d3, g), s_), fm(fm(2.0f, c_), b));
                    p = fm(s_, r);
                    d2 = fa(g, p);
                    g = fs(fm(c_, r), b);
                    wc2 = c_; ws2 = s_;
                }
                rot2col(z11, z21, z31, z12, z22, z32, wc1, ws1);   // rotcf(1,2)
                rot2col(z12, z22, z32, z13, z23, z33, wc2, ws2);   // rotcf(2,3)
                d3 = fs(d3, p); e2 = g;
            }
        }
    }
    // ascending selection sort with column swaps (ssteqr tail)
    for (int ii = 2; ii <= 3; ++ii) {
        int i = ii - 1, kk = i; float p = RD(i);
        for (int j = ii; j <= 3; ++j) { float dj = RD(j); if (dj < p) { kk = j; p = dj; } }
        if (kk != i) {
            WRD(kk, RD(i)); WRD(i, p);
            if (i == 1 && kk == 2)      { SWAPC(z11, z12); SWAPC(z21, z22); SWAPC(z31, z32); }
            else if (i == 1 && kk == 3) { SWAPC(z11, z13); SWAPC(z21, z23); SWAPC(z31, z33); }
            else                        { SWAPC(z12, z13); SWAPC(z22, z23); SWAPC(z32, z33); }
        }
    }
    // sormtr: Z := H1 * Z (rows 2..3), slarf/sger op order
    if (tau != 0.0f) {
        float ss, t;
        ss = fa(z21, fm(v3, z31)); t = fm(tau, ss); z21 = fs(z21, t); z31 = fs(z31, fm(t, v3));
        ss = fa(z22, fm(v3, z32)); t = fm(tau, ss); z22 = fs(z22, t); z32 = fs(z32, fm(t, v3));
        ss = fa(z23, fm(v3, z33)); t = fm(tau, ss); z23 = fs(z23, t); z33 = fs(z33, fm(t, v3));
    }
    v1o = z11; v2o = z21; v3o = z31;
}

// ---------------- JAX threefry2x32 (key(42) noise reproduction)
__device__ void threefry2x32_(unsigned k0, unsigned k1, unsigned c0, unsigned c1,
                              unsigned& o0, unsigned& o1) {
    const unsigned rot[8] = {13u, 15u, 26u, 6u, 17u, 29u, 16u, 24u};
    unsigned ks[3] = {k0, k1, k0 ^ k1 ^ 0x1BD11BDAu};
    unsigned x0 = c0 + k0, x1 = c1 + k1;
    for (int blk = 0; blk < 5; ++blk) {
        const unsigned* r = &rot[(blk & 1) * 4];
        for (int i = 0; i < 4; ++i) {
            x0 += x1;
            x1 = (x1 << r[i]) | (x1 >> (32 - r[i]));
            x1 ^= x0;
        }
        x0 += ks[(blk + 1) % 3];
        x1 += ks[(blk + 2) % 3] + (unsigned)(blk + 1);
    }
    o0 = x0; o1 = x1;
}

// noise[j] = (uniform(key(42),(100,3))[j,j] - 0.5) * 1e-8 ; flat idx m = 4*j
__device__ float noise_diag_(int j) {
    unsigned m = (unsigned)(4 * j);
    unsigned o0, o1;
    threefry2x32_(0u, 42u, m, 150u + m, o0, o1);  // m<150 -> first-half output
    unsigned bits = (o0 >> 9) | 0x3f800000u;
    float u = fs(__uint_as_float(bits), 1.0f);    // [0,1)
    return fm(fs(u, 0.5f), 1e-8f);
}

__device__ __forceinline__ float angf(float ax, float ay, float az,
                                      float bx, float by, float bz) {
    float cx = ay * bz - az * by;
    float cy = az * bx - ax * bz;
    float cz = ax * by - ay * bx;
    float cn = sqrtf(cx * cx + cy * cy + cz * cz);
    float d  = ax * bx + ay * by + az * bz;
    return atan2f(cn, d);
}

// ---------------------------------------------------------------- grid build

__global__ void k_zero(int* __restrict__ hist) {
    hist[threadIdx.x] = 0;   // launched with NCELL threads, 1 block
}

__global__ void k_prep(const float* __restrict__ pts, float4* __restrict__ pos4,
                       int* __restrict__ pcell, int* __restrict__ hist, int n) {
    int i = blockIdx.x * blockDim.x + threadIdx.x;
    if (i < n) {
        float x = pts[i * 3], y = pts[i * 3 + 1], z = pts[i * 3 + 2];
        float sq = fa(fa(fm(x, x), fm(y, y)), fm(z, z));
        pos4[i] = make_float4(x, y, z, sq);
        int cx = (int)(x * 8.0f); cx = cx < 0 ? 0 : (cx > GRD - 1 ? GRD - 1 : cx);
        int cy = (int)(y * 8.0f); cy = cy < 0 ? 0 : (cy > GRD - 1 ? GRD - 1 : cy);
        int cz = (int)(z * 8.0f); cz = cz < 0 ? 0 : (cz > GRD - 1 ? GRD - 1 : cz);
        int cid = (cz * GRD + cy) * GRD + cx;
        pcell[i] = cid;
        atomicAdd(&hist[cid], 1);
    }
}

// single block, NCELL threads: exclusive scan of hist -> start[0..NCELL], cursor copy
__global__ __launch_bounds__(NCELL) void k_scan(const int* __restrict__ hist,
                                                int* __restrict__ start,
                                                int* __restrict__ cursor) {
    __shared__ int s[NCELL];
    int t = threadIdx.x;
    int v = hist[t];
    s[t] = v;
    __syncthreads();
    for (int off = 1; off < NCELL; off <<= 1) {
        int x = (t >= off) ? s[t - off] : 0;
        __syncthreads();
        s[t] += x;
        __syncthreads();
    }
    int ex = s[t] - v;
    start[t] = ex;
    cursor[t] = ex;
    if (t == NCELL - 1) start[NCELL] = s[t];
}

__global__ void k_scatter(const int* __restrict__ pcell, int* __restrict__ cursor,
                          int* __restrict__ order, int n) {
    int i = blockIdx.x * blockDim.x + threadIdx.x;
    if (i < n) {
        int slot = atomicAdd(&cursor[pcell[i]], 1);
        order[slot] = i;
    }
}

// ---------------------------------------------------------------- grid KNN
#define KEY_WORST 0xC0001FFFFFFFFFFFull
#define CBUF 128

__global__ __launch_bounds__(256) void k_knn(const float4* __restrict__ pos4,
                                             const int* __restrict__ order,
                                             const int* __restrict__ cstart,
                                             int* __restrict__ cols, int n) {
    __shared__ unsigned long long sbuf[4][CBUF];
    __shared__ int scnt[4];

    int lane = threadIdx.x & 63;
    int wv = threadIdx.x >> 6;
    int io = blockIdx.x * 4 + wv;
    if (io >= n) return;   // no block-wide barriers below: per-wave exit is safe

    float4 P = pos4[io];
    int cx = (int)(P.x * 8.0f); cx = cx < 0 ? 0 : (cx > GRD - 1 ? GRD - 1 : cx);
    int cy = (int)(P.y * 8.0f); cy = cy < 0 ? 0 : (cy > GRD - 1 ? GRD - 1 : cy);
    int cz = (int)(P.z * 8.0f); cz = cz < 0 ? 0 : (cz > GRD - 1 ? GRD - 1 : cz);

    unsigned T = 0xFFFFFFFFu;
    int xlo = 0, xhi = 0, ylo = 0, yhi = 0, zlo = 0, zhi = 0;

    for (int r = 1; r < 16; ++r) {
        xlo = cx - r; if (xlo < 0) xlo = 0;
        xhi = cx + r; if (xhi > GRD - 1) xhi = GRD - 1;
        ylo = cy - r; if (ylo < 0) ylo = 0;
        yhi = cy + r; if (yhi > GRD - 1) yhi = GRD - 1;
        zlo = cz - r; if (zlo < 0) zlo = 0;
        zhi = cz + r; if (zhi > GRD - 1) zhi = GRD - 1;

        // ---- pass 1: per-lane top-2 raw-bit d2 over the cell block
        unsigned b0 = 0xFFFFFFFFu, b1 = 0xFFFFFFFFu;
        for (int zz = zlo; zz <= zhi; ++zz)
            for (int yy = ylo; yy <= yhi; ++yy) {
                int rowb = (zz * GRD + yy) * GRD;   // x-cells contiguous
                int jb = cstart[rowb + xlo];
                int je = cstart[rowb + xhi + 1];
                for (int t = jb + lane; t < je; t += 64) {
                    int j = order[t];
                    float4 Q = pos4[j];
                    float g = fm(P.x, Q.x);
                    g = fmaf(P.y, Q.y, g);
                    g = fmaf(P.z, Q.z, g);
                    float d2 = fs(fa(P.w, Q.w), fm(2.0f, g));
                    unsigned u = __float_as_uint(d2);
                    u = (j == io) ? 0xFFFFFFFFu : u;
                    unsigned lo = umin32(b0, u);
                    unsigned hi = umax32(b0, u);
                    b0 = lo;
                    b1 = umin32(b1, hi);
                }
            }

        // ---- 13th smallest of per-lane top-2 union: upper bound on true 13th
        {
            unsigned h0 = b0, h1 = b1;
            T = 0xFFFFFFFFu;
            for (int rr = 0; rr < KNB + 1; ++rr) {
                unsigned mn = h0;
#pragma unroll
                for (int off = 32; off >= 1; off >>= 1) {
                    unsigned o = (unsigned)__shfl_xor((int)mn, off, 64);
                    mn = umin32(mn, o);
                }
                unsigned long long bl = __ballot(h0 == mn);
                int first = __ffsll(bl) - 1;
                if (lane == first) { h0 = h1; h1 = 0xFFFFFFFFu; }
                T = mn;
            }
        }

        // ---- sufficiency: all true top-12 inside the searched block?
        bool cover = (xlo == 0) && (xhi == GRD - 1) && (ylo == 0) && (yhi == GRD - 1)
                  && (zlo == 0) && (zhi == GRD - 1);
        if (cover) break;
        if (T != 0xFFFFFFFFu) {
            // distance from P to nearest in-cube face of the searched block
            float gmin = 1e30f;
            if (xlo > 0)       gmin = fminf(gmin, fs(P.x, (float)xlo * 0.125f));
            if (xhi < GRD - 1) gmin = fminf(gmin, fs((float)(xhi + 1) * 0.125f, P.x));
            if (ylo > 0)       gmin = fminf(gmin, fs(P.y, (float)ylo * 0.125f));
            if (yhi < GRD - 1) gmin = fminf(gmin, fs((float)(yhi + 1) * 0.125f, P.y));
            if (zlo > 0)       gmin = fminf(gmin, fs(P.z, (float)zlo * 0.125f));
            if (zhi < GRD - 1) gmin = fminf(gmin, fs((float)(zhi + 1) * 0.125f, P.z));
            float g2 = fm(fm(gmin, gmin), 0.9995f);   // margin >> f32 rounding
            if (__uint_as_float(T) <= g2) break;
        }
        // else: expand ring (rare: anomalously sparse neighborhoods)
    }

    // ---- pass 2: compact candidates with raw bits <= T into the wave buffer
    if (lane == 0) scnt[wv] = 0;
    __builtin_amdgcn_wave_barrier();
    for (int zz = zlo; zz <= zhi; ++zz)
        for (int yy = ylo; yy <= yhi; ++yy) {
            int rowb = (zz * GRD + yy) * GRD;
            int jb = cstart[rowb + xlo];
            int je = cstart[rowb + xhi + 1];
            for (int t = jb + lane; t < je; t += 64) {
                int j = order[t];
                float4 Q = pos4[j];
                float g = fm(P.x, Q.x);
                g = fmaf(P.y, Q.y, g);
                g = fmaf(P.z, Q.z, g);
                float d2 = fs(fa(P.w, Q.w), fm(2.0f, g));
                unsigned u = __float_as_uint(d2);
                bool c = (u <= T) && (j != io);
                unsigned long long bl = __ballot(c);
                if (bl) {
                    int leader = __ffsll(bl) - 1;
                    int base = 0;
                    if (lane == leader)
                        base = atomicAdd(&scnt[wv], (int)__popcll(bl));
                    base = __shfl(base, leader, 64);
                    if (c) {
                        int pos = base + (int)__popcll(bl & ((1ull << lane) - 1ull));
                        unsigned us = u ^ (unsigned)(((int)u >> 31) | 0x80000000);
                        unsigned long long kb = (((unsigned long long)us << 13) | (unsigned)j)
                                                | 0xC000000000000000ull;
                        if (pos < CBUF) sbuf[wv][pos] = kb;
                    }
                }
            }
        }
    __builtin_amdgcn_wave_barrier();
    int cnt = scnt[wv];
    if (cnt > CBUF) cnt = CBUF;

    // ---- exact top-12 from buffer (packed keys as negative doubles: fmax = min-key)
    double k0 = __longlong_as_double((long long)KEY_WORST);
    double k1 = __longlong_as_double((long long)KEY_WORST);
    if (lane < cnt) k0 = __longlong_as_double((long long)sbuf[wv][lane]);
    if (lane + 64 < cnt) k1 = __longlong_as_double((long long)sbuf[wv][lane + 64]);
    double mykey = __longlong_as_double((long long)KEY_WORST);
    for (int rr = 0; rr < KNB; ++rr) {
        double mx = fmax(k0, k1);
#pragma unroll
        for (int off = 32; off >= 1; off >>= 1)
            mx = fmax(mx, __shfl_xor(mx, off, 64));
        if (k0 == mx) k0 = __longlong_as_double((long long)KEY_WORST);
        else if (k1 == mx) k1 = __longlong_as_double((long long)KEY_WORST);
        if (lane == rr) mykey = mx;
    }
    if (lane < KNB) {
        unsigned long long bits = (unsigned long long)__double_as_longlong(mykey);
        unsigned j = (unsigned)(bits & 0x1FFFu);
        unsigned u = (unsigned)((bits >> 13) & 0xFFFFFFFFull);
        unsigned ob = (u & 0x80000000u) ? (u ^ 0x80000000u) : ~u;
        float d2 = __uint_as_float(ob);
        cols[io * KNB + lane] = (d2 <= 0.25f) ? (int)j : io;
    }
}

// ---------------------------------------------------------------- normals
__global__ __launch_bounds__(64) void k_normals(const float4* __restrict__ pos4,
                                                const int* __restrict__ cols,
                                                float4* __restrict__ nrm4,
                                                float* __restrict__ out, int n) {
    int i = blockIdx.x * blockDim.x + threadIdx.x;
    if (i >= n) return;

    float qx[KNB], qy[KNB], qz[KNB];
#pragma unroll
    for (int k = 0; k < KNB; ++k) {
        float4 q = pos4[cols[i * KNB + k]];
        qx[k] = q.x; qy[k] = q.y; qz[k] = q.z;
    }
    // mean: f32 sequential over k
    float sx = qx[0], sy = qy[0], sz = qz[0];
#pragma unroll
    for (int k = 1; k < KNB; ++k) { sx = fa(sx, qx[k]); sy = fa(sy, qy[k]); sz = fa(sz, qz[k]); }
    float mx = sx / 12.0f, my = sy / 12.0f, mz = sz / 12.0f;
    // cov: f32 sequential over k (np.einsum order)
    float c00 = 0, c10 = 0, c20 = 0, c11 = 0, c21 = 0, c22 = 0;
#pragma unroll
    for (int k = 0; k < KNB; ++k) {
        float dx = fs(qx[k], mx), dy = fs(qy[k], my), dz = fs(qz[k], mz);
        c00 = fa(c00, fm(dx, dx));
        c10 = fa(c10, fm(dy, dx));
        c20 = fa(c20, fm(dz, dx));
        c11 = fa(c11, fm(dy, dy));
        c21 = fa(c21, fm(dz, dy));
        c22 = fa(c22, fm(dz, dz));
    }
    c00 = c00 / 12.0f; c10 = c10 / 12.0f; c20 = c20 / 12.0f;
    c11 = c11 / 12.0f; c21 = c21 / 12.0f; c22 = c22 / 12.0f;
    // + jnp.diag(noise): np eigh reads lower, A[i][j] += v[j]
    float v0 = noise_diag_(0), v1 = noise_diag_(1), v2 = noise_diag_(2);
    float a00 = fa(c00, v0), a10 = fa(c10, v0), a20 = fa(c20, v0);
    float a11 = fa(c11, v1), a21 = fa(c21, v1), a22 = fa(c22, v2);
    float e1, e2, e3;
    eig3_smallest_reg(a00, a10, a20, a11, a21, a22, e1, e2, e3);
    nrm4[i] = make_float4(e1, e2, e3, 0.0f);
    out[i]         = e1;
    out[n + i]     = e2;
    out[2 * n + i] = e3;
}

// ---------------------------------------------------------------- MLP chain
// 24 threads/point: 12 edges x 2 hidden-halves. l-MLPs split across halves
// (LDS partial reduce); g-MLPs distribute 32 hidden units across 24 lanes.
// All LDS strides odd (17/13) -> conflict-free.

struct WPtrs { const float* p[28]; };

// half of an l-MLP: this thread computes hidden units [hf*NH/2, (hf+1)*NH/2)
template <int NI, int NH, int NO>
__device__ __forceinline__ void mlp_half(const float* __restrict__ w1, const float* __restrict__ b1,
                                         const float* __restrict__ w2, const float* __restrict__ b2,
                                         const float* in, float* out, int hf) {
#pragma unroll
    for (int o = 0; o < NO; ++o) out[o] = hf ? 0.0f : b2[o];
    const int HH = NH / 2;
    int h0 = hf * HH;
#pragma unroll
    for (int hi = 0; hi < HH; ++hi) {
        int h = h0 + hi;
        float hh = b1[h];
#pragma unroll
        for (int ii = 0; ii < NI; ++ii) hh = fmaf(in[ii], w1[ii * NH + h], hh);
        hh = fmaxf(hh, 0.0f);
#pragma unroll
        for (int o = 0; o < NO; ++o) out[o] = fmaf(hh, w2[h * NO + o], out[o]);
    }
}

// g-MLP (NH=32) partial: thread q handles h=q, plus h=24+q when q<8.
template <int NI, int NO>
__device__ __forceinline__ void gmlp_part(const float* __restrict__ w1, const float* __restrict__ b1,
                                          const float* __restrict__ w2, const float* __restrict__ b2,
                                          const float* in, float* pout, int q) {
#pragma unroll
    for (int o = 0; o < NO; ++o) pout[o] = (q == 0) ? b2[o] : 0.0f;
    {
        float hh = b1[q];
#pragma unroll
        for (int ii = 0; ii < NI; ++ii) hh = fmaf(in[ii], w1[ii * 32 + q], hh);
        hh = fmaxf(hh, 0.0f);
#pragma unroll
        for (int o = 0; o < NO; ++o) pout[o] = fmaf(hh, w2[q * NO + o], pout[o]);
    }
    if (q < 8) {
        int h = 24 + q;
        float hh = b1[h];
#pragma unroll
        for (int ii = 0; ii < NI; ++ii) hh = fmaf(in[ii], w1[ii * 32 + h], hh);
        hh = fmaxf(hh, 0.0f);
#pragma unroll
        for (int o = 0; o < NO; ++o) pout[o] = fmaf(hh, w2[h * NO + o], pout[o]);
    }
}

#define SCR(pp, qq, oo) s_scr[((pp) * 24 + (qq)) * 17 + (oo)]
#define SX(pp, kk, oo)  s_x[((pp) * 12 + (kk)) * 17 + (oo)]
#define SM(pp, oo)      s_m[(pp) * 17 + (oo)]
#define GFV(pp, oo)     s_g[(pp) * 13 + (oo)]
#define SLG(pp, kk)     s_log[(pp) * 13 + (kk)]

__global__ __launch_bounds__(384, 3) void k_mlp(const float4* __restrict__ pos4,
                                                const int* __restrict__ cols,
                                                const float4* __restrict__ nrm4,
                                                WPtrs wp, float* __restrict__ out, int n) {
    __shared__ float s_scr[16 * 24 * 17];   // partial buffers (l-halves / g-lanes)
    __shared__ float s_x[16 * 12 * 17];     // per-edge x (for means)
    __shared__ float s_m[16 * 17];          // per-point means
    __shared__ float s_g[16 * 13];          // g-MLP outputs
    __shared__ float s_log[16 * 13];        // logits
    __shared__ float s_red[16 * 2];         // softmax max/sum

    int t = threadIdx.x;
    int p = t / 24, q = t - p * 24;
    int k = q % 12, hf = q / 12;
    int nn = blockIdx.x * 16 + p;
    bool act = (nn < n);

    float cx = 0, cy = 0, cz = 0, nrx = 0, nry = 0, nrz = 0;
    float xr[16];

    // ---- stage A: edge features + l1 (half)
    if (act) {
        int col = cols[nn * 12 + k];
        float4 P = pos4[nn], Q = pos4[col];
        cx = Q.x - P.x; cy = Q.y - P.y; cz = Q.z - P.z;
        float dist = sqrtf(cx * cx + cy * cy + cz * cz);
        float4 NR = nrm4[nn], NC = nrm4[col];
        nrx = NR.x; nry = NR.y; nrz = NR.z;
        float a1 = angf(nrx, nry, nrz, cx, cy, cz);
        float a2 = angf(NC.x, NC.y, NC.z, cx, cy, cz);
        float a3 = angf(nrx, nry, nrz, NC.x, NC.y, NC.z);
        float in7[7] = {cx, cy, cz, dist, a1, a2, a3};
        float px[16];
        mlp_half<7, 32, 16>(wp.p[0], wp.p[1], wp.p[2], wp.p[3], in7, px, hf);
#pragma unroll
        for (int o = 0; o < 16; ++o) SCR(p, q, o) = px[o];
    }
    __syncthreads();
    if (act) {
#pragma unroll
        for (int o = 0; o < 16; ++o) xr[o] = SCR(p, k, o) + SCR(p, 12 + k, o);
        if (hf == 0)
#pragma unroll
            for (int o = 0; o < 16; ++o) SX(p, k, o) = xr[o];
    }
    __syncthreads();

    // ---- stage B: mean + g1 (lane-parallel)
    if (act && q < 16) {
        float s = 0.0f;
        for (int kk = 0; kk < 12; ++kk) s += SX(p, kk, q);
        SM(p, q) = s / 12.0f;
    }
    __syncthreads();
    if (act) {
        float gin[19];
#pragma unroll
        for (int ii = 0; ii < 16; ++ii) gin[ii] = SM(p, ii);
        gin[16] = nrx; gin[17] = nry; gin[18] = nrz;
        float pg[8];
        gmlp_part<19, 8>(wp.p[4], wp.p[5], wp.p[6], wp.p[7], gin, pg, q);
#pragma unroll
        for (int o = 0; o < 8; ++o) SCR(p, q, o) = pg[o];
    }
    __syncthreads();
    if (act && q < 8) {
        float s = 0.0f;
        for (int j = 0; j < 24; ++j) s += SCR(p, j, q);
        GFV(p, q) = s;
    }
    __syncthreads();

    // ---- stage C: l2 (half)
    if (act) {
        float in24[24];
#pragma unroll
        for (int o = 0; o < 16; ++o) in24[o] = xr[o];
#pragma unroll
        for (int o = 0; o < 8; ++o) in24[16 + o] = GFV(p, o);
        float px[16];
        mlp_half<24, 32, 16>(wp.p[8], wp.p[9], wp.p[10], wp.p[11], in24, px, hf);
#pragma unroll
        for (int o = 0; o < 16; ++o) SCR(p, q, o) = px[o];
    }
    __syncthreads();
    if (act) {
#pragma unroll
        for (int o = 0; o < 16; ++o) xr[o] = SCR(p, k, o) + SCR(p, 12 + k, o);
        if (hf == 0)
#pragma unroll
            for (int o = 0; o < 16; ++o) SX(p, k, o) = xr[o];
    }
    __syncthreads();

    // ---- stage D: mean + g2
    if (act && q < 16) {
        float s = 0.0f;
        for (int kk = 0; kk < 12; ++kk) s += SX(p, kk, q);
        SM(p, q) = s / 12.0f;
    }
    __syncthreads();
    if (act) {
        float gin[16];
#pragma unroll
        for (int ii = 0; ii < 16; ++ii) gin[ii] = SM(p, ii);
        float pg[8];
        gmlp_part<16, 8>(wp.p[12], wp.p[13], wp.p[14], wp.p[15], gin, pg, q);
#pragma unroll
        for (int o = 0; o < 8; ++o) SCR(p, q, o) = pg[o];
    }
    __syncthreads();
    if (act && q < 8) {
        float s = 0.0f;
        for (int j = 0; j < 24; ++j) s += SCR(p, j, q);
        GFV(p, q) = s;
    }
    __syncthreads();

    // ---- stage E: l3 (half)
    if (act) {
        float in24[24];
#pragma unroll
        for (int o = 0; o < 16; ++o) in24[o] = xr[o];
#pragma unroll
        for (int o = 0; o < 8; ++o) in24[16 + o] = GFV(p, o);
        float px[16];
        mlp_half<24, 32, 16>(wp.p[16], wp.p[17], wp.p[18], wp.p[19], in24, px, hf);
#pragma unroll
        for (int o = 0; o < 16; ++o) SCR(p, q, o) = px[o];
    }
    __syncthreads();
    if (act) {
#pragma unroll
        for (int o = 0; o < 16; ++o) xr[o] = SCR(p, k, o) + SCR(p, 12 + k, o);
        if (hf == 0)
#pragma unroll
            for (int o = 0; o < 16; ++o) SX(p, k, o) = xr[o];
    }
    __syncthreads();

    // ---- stage F: mean + g3 (12 outputs)
    if (act && q < 16) {
        float s = 0.0f;
        for (int kk = 0; kk < 12; ++kk) s += SX(p, kk, q);
        SM(p, q) = s / 12.0f;
    }
    __syncthreads();
    if (act) {
        float gin[16];
#pragma unroll
        for (int ii = 0; ii < 16; ++ii) gin[ii] = SM(p, ii);
        float pg[12];
        gmlp_part<16, 12>(wp.p[20], wp.p[21], wp.p[22], wp.p[23], gin, pg, q);
#pragma unroll
        for (int o = 0; o < 12; ++o) SCR(p, q, o) = pg[o];
    }
    __syncthreads();
    if (act && q < 12) {
        float s = 0.0f;
        for (int j = 0; j < 24; ++j) s += SCR(p, j, q);
        GFV(p, q) = s;
    }
    __syncthreads();

    // ---- stage G: quat->mat (computed redundantly per thread) + l4 (half)
    if (act) {
        float g0 = GFV(p, 0), g1v = GFV(p, 1), g2v = GFV(p, 2), g3v = GFV(p, 3);
        float qn = sqrtf(g0 * g0 + g1v * g1v + g2v * g2v + g3v * g3v) + 1e-8f;
        float qw = g0 / qn, qxx = g1v / qn, qyy = g2v / qn, qzz = g3v / qn;
        float m0 = 1.0f - 2.0f * (qyy * qyy + qzz * qzz);
        float m1 = 2.0f * (qxx * qyy - qzz * qw);
        float m2 = 2.0f * (qxx * qzz + qyy * qw);
        float m3 = 2.0f * (qxx * qyy + qzz * qw);
        float m4 = 1.0f - 2.0f * (qxx * qxx + qzz * qzz);
        float m5 = 2.0f * (qyy * qzz - qxx * qw);
        float m6 = 2.0f * (qxx * qzz - qyy * qw);
        float m7 = 2.0f * (qyy * qzz + qxx * qw);
        float m8 = 1.0f - 2.0f * (qxx * qxx + qyy * qyy);
        float r0 = m0 * cx + m1 * cy + m2 * cz;
        float r1 = m3 * cx + m4 * cy + m5 * cz;
        float r2 = m6 * cx + m7 * cy + m8 * cz;
        float in27[27];
#pragma unroll
        for (int o = 0; o < 16; ++o) in27[o] = xr[o];
#pragma unroll
        for (int o = 0; o < 8; ++o) in27[16 + o] = GFV(p, 4 + o);
        in27[24] = r0; in27[25] = r1; in27[26] = r2;
        float plg[1];
        mlp_half<27, 64, 1>(wp.p[24], wp.p[25], wp.p[26], wp.p[27], in27, plg, hf);
        SCR(p, q, 0) = plg[0];
    }
    __syncthreads();
    if (act && hf == 0) SLG(p, k) = SCR(p, k, 0) + SCR(p, 12 + k, 0);
    __syncthreads();

    // ---- stage H: softmax over the 12 edges (same op order as reference)
    if (act && q == 0) {
        float mx = SLG(p, 0);
        for (int kk = 1; kk < 12; ++kk) mx = fmaxf(mx, SLG(p, kk));
        float se = 0;
        for (int kk = 0; kk < 12; ++kk) se += expf(SLG(p, kk) - mx);
        s_red[p * 2] = mx; s_red[p * 2 + 1] = se;
    }
    __syncthreads();
    if (act && hf == 0) {
        float v = expf(SLG(p, k) - s_red[p * 2]) / s_red[p * 2 + 1];
        out[3 * n + k * n + nn] = v;
    }
}

// ---------------------------------------------------------------- launch

extern "C" void kernel_launch(void* const* d_in, const int* in_sizes, int n_in,
                              void* d_out, int out_size, void* d_ws, size_t ws_size,
                              hipStream_t stream) {
    const float* pts = (const float*)d_in[0];
    int n = in_sizes[0] / 3;

    char* ws = (char*)d_ws;
    float4* pos4  = (float4*)ws;                            // n*16 B
    int*    cols  = (int*)(ws + (size_t)n * 16);            // n*48 B
    float4* nrm4  = (float4*)(ws + (size_t)n * 64);         // n*16 B
    int*    pcell = (int*)(ws + (size_t)n * 80);            // n*4 B
    int*    order = (int*)(ws + (size_t)n * 84);            // n*4 B
    int*    hist  = (int*)(ws + (size_t)n * 88);            // NCELL ints
    int*    start = hist + NCELL;                           // NCELL+1 ints
    int*    cursor = start + NCELL + 1;                     // NCELL ints
    float*  out = (float*)d_out;

    WPtrs wp;
    for (int a = 0; a < 28; ++a) wp.p[a] = (const float*)d_in[a + 1];

    k_zero<<<1, NCELL, 0, stream>>>(hist);
    k_prep<<<(n + 255) / 256, 256, 0, stream>>>(pts, pos4, pcell, hist, n);
    k_scan<<<1, NCELL, 0, stream>>>(hist, start, cursor);
    k_scatter<<<(n + 255) / 256, 256, 0, stream>>>(pcell, cursor, order, n);
    k_knn<<<(n + 3) / 4, 256, 0, stream>>>(pos4, order, start, cols, n);
    k_normals<<<(n + 63) / 64, 64, 0, stream>>>(pos4, cols, nrm4, out, n);
    // 24 threads/point (12 edges x 2 hidden-halves), 16 points/block
    k_mlp<<<(n + 15) / 16, 384, 0, stream>>>(pos4, cols, nrm4, wp, out, n);
}

// Round 4
// 254.425 us; speedup vs baseline: 1.1274x; 1.1274x over previous
//
#include <hip/hip_runtime.h>
#include <math.h>

#define KNB 12
#define GRD 8
#define NCELL (GRD * GRD * GRD)   // 512 cells, cell edge = 0.125

// ---------------------------------------------------------------- helpers

__device__ __forceinline__ unsigned umin32(unsigned a, unsigned b) {
    unsigned r; asm("v_min_u32 %0, %1, %2" : "=v"(r) : "v"(a), "v"(b)); return r;
}
__device__ __forceinline__ unsigned umax32(unsigned a, unsigned b) {
    unsigned r; asm("v_max_u32 %0, %1, %2" : "=v"(r) : "v"(a), "v"(b)); return r;
}

// ---------------- f32 no-contract primitives (match CPU netlib rounding)
__device__ __forceinline__ float fm(float a, float b) { return __fmul_rn(a, b); }
__device__ __forceinline__ float fa(float a, float b) { return __fadd_rn(a, b); }
__device__ __forceinline__ float fs(float a, float b) { return __fsub_rn(a, b); }
__device__ __forceinline__ float fsignf(float a, float b) { return (b >= 0.0f) ? fabsf(a) : -fabsf(a); }

__device__ float slapy2_(float x, float y) {
    float xa = fabsf(x), ya = fabsf(y);
    float w = fmaxf(xa, ya), z = fminf(xa, ya);
    if (z == 0.0f) return w;
    float q = z / w;
    return fm(w, __fsqrt_rn(fa(1.0f, fm(q, q))));
}

// LAPACK >=3.10 slartg: c = |f|/d >= 0, r = sign(f)*d
__device__ void slartg_(float f, float g, float& c, float& s, float& r) {
    if (g == 0.0f) { c = 1.0f; s = 0.0f; r = f; }
    else if (f == 0.0f) { c = 0.0f; s = (g >= 0.0f) ? 1.0f : -1.0f; r = fabsf(g); }
    else {
        float d = __fsqrt_rn(fa(fm(f, f), fm(g, g)));
        c = fabsf(f) / d;
        r = (f >= 0.0f) ? d : -d;
        s = g / r;
    }
}

// netlib slaev2 (f32): eigvec of RT1 is (cs1, sn1)
__device__ void slaev2_(float a, float b, float cc,
                        float& rt1, float& rt2, float& cs1, float& sn1) {
    float sm = fa(a, cc), df = fs(a, cc), adf = fabsf(df);
    float tb = fa(b, b), ab = fabsf(tb);
    float acmx, acmn;
    if (fabsf(a) > fabsf(cc)) { acmx = a; acmn = cc; } else { acmx = cc; acmn = a; }
    float rt;
    if (adf > ab)      { float q = ab / adf; rt = fm(adf, __fsqrt_rn(fa(1.0f, fm(q, q)))); }
    else if (adf < ab) { float q = adf / ab; rt = fm(ab,  __fsqrt_rn(fa(1.0f, fm(q, q)))); }
    else               rt = fm(ab, __fsqrt_rn(2.0f));
    int sgn1;
    if (sm < 0.0f) {
        rt1 = fm(0.5f, fs(sm, rt)); sgn1 = -1;
        rt2 = fs(fm(acmx / rt1, acmn), fm(b / rt1, b));
    } else if (sm > 0.0f) {
        rt1 = fm(0.5f, fa(sm, rt)); sgn1 = 1;
        rt2 = fs(fm(acmx / rt1, acmn), fm(b / rt1, b));
    } else { rt1 = fm(0.5f, rt); rt2 = fm(-0.5f, rt); sgn1 = 1; }
    int sgn2; float cs;
    if (df >= 0.0f) { cs = fa(df, rt); sgn2 = 1; } else { cs = fs(df, rt); sgn2 = -1; }
    float acs = fabsf(cs);
    if (acs > ab) {
        float ct = -tb / cs;
        sn1 = 1.0f / __fsqrt_rn(fa(1.0f, fm(ct, ct)));
        cs1 = fm(ct, sn1);
    } else {
        if (ab == 0.0f) { cs1 = 1.0f; sn1 = 0.0f; }
        else {
            float tn = -cs / tb;
            cs1 = 1.0f / __fsqrt_rn(fa(1.0f, fm(tn, tn)));
            sn1 = fm(tn, cs1);
        }
    }
    if (sgn1 == sgn2) { float tn = cs1; cs1 = -sn1; sn1 = tn; }
}

// slasr single rotation on Z columns (j1,j2): a* = col j1, b* = col j2.
// Literal netlib expression order.
__device__ __forceinline__ void rot2col(float& a1, float& a2, float& a3,
                                        float& b1, float& b2, float& b3,
                                        float ct, float st) {
    float t;
    t = b1; b1 = fs(fm(ct, t), fm(st, a1)); a1 = fa(fm(st, t), fm(ct, a1));
    t = b2; b2 = fs(fm(ct, t), fm(st, a2)); a2 = fa(fm(st, t), fm(ct, a2));
    t = b3; b3 = fs(fm(ct, t), fm(st, a3)); a3 = fa(fm(st, t), fm(ct, a3));
}

// dynamic-index accessors over NAMED registers (cndmask selects, no memory).
#define RD(i)    ((i) == 1 ? d1 : ((i) == 2 ? d2 : d3))
#define WRD(i,v) do { float _t = (v); if ((i) == 1) d1 = _t; else if ((i) == 2) d2 = _t; else d3 = _t; } while (0)
#define RE(i)    ((i) == 1 ? e1 : e2)
#define WRE(i,v) do { float _t = (v); if ((i) == 1) e1 = _t; else e2 = _t; } while (0)
#define SWAPC(a,b) do { float _t = (a); (a) = (b); (b) = _t; } while (0)

// Faithful f32 port of ssyevd path (ssytd2 'L' -> ssteqr 'I' -> sormtr) for a
// 3x3 symmetric-lower matrix; eigvec of smallest eigenvalue, LAPACK signs.
// Pure-register storage: identical op sequence to the LDS version (bit-equal).
__device__ void eig3_smallest_reg(float a00, float a10, float a20,
                                  float a11, float a21, float a22,
                                  float& v1o, float& v2o, float& v3o) {
    float z11 = 1.0f, z21 = 0.0f, z31 = 0.0f;
    float z12 = 0.0f, z22 = 1.0f, z32 = 0.0f;
    float z13 = 0.0f, z23 = 0.0f, z33 = 1.0f;
    float d1, d2, d3, e1, e2;
    float wc1 = 0.0f, wc2 = 0.0f, ws1 = 0.0f, ws2 = 0.0f;

    // --- ssytd2 'L' (single Householder on column 1), faithful BLAS op order
    float tau = 0.0f, v3 = 0.0f;
    d1 = a00;
    if (a20 != 0.0f) {
        float xn = fabsf(a20);                      // snrm2 length-1
        float beta = -fsignf(slapy2_(a10, xn), a10);
        tau = fs(beta, a10) / beta;
        float rinv = 1.0f / fs(a10, beta);          // sscal: recip then mul
        v3 = fm(a20, rinv);
        e1 = beta;
        // ssymv lower n=2: w = tau * A22 * (1, v3)
        float w1 = fa(fm(tau, a11), fm(tau, fm(a21, v3)));
        float w2 = fa(fm(tau, a21), fm(fm(tau, v3), a22));
        float dot = fa(w1, fm(w2, v3));
        float al = fm(fm(-0.5f, tau), dot);
        w1 = fa(w1, al);
        w2 = fa(w2, fm(al, v3));
        d2 = fs(fs(a11, w1), w1);
        e2 = fs(fs(a21, fm(v3, w1)), w2);
        d3 = fs(fs(a22, fm(v3, w2)), fm(w2, v3));
    } else {
        e1 = a10; d2 = a11; e2 = a21; d3 = a22;
    }

    // --- ssteqr 'I' (f32 constants)
    const float eps = 5.9604645e-8f;        // slamch('E') = 2^-24
    const float eps2 = 3.5527137e-15f;      // eps^2
    const float safmin = 1.17549435e-38f;   // slamch('S')
    int jtot = 0; const int nmaxit = 90;
    int l1 = 1;
    while (l1 <= 3) {
        if (l1 > 1) WRE(l1 - 1, 0.0f);
        int m;
        for (m = l1; m <= 2; ++m) {
            float tst = fabsf(RE(m));
            if (tst == 0.0f) break;
            if (tst <= fm(fm(__fsqrt_rn(fabsf(RD(m))), __fsqrt_rn(fabsf(RD(m + 1)))), eps)) {
                WRE(m, 0.0f); break;
            }
        }
        int l = l1, lend = m;
        l1 = m + 1;
        if (lend == l) continue;
        if (fabsf(RD(lend)) < fabsf(RD(l))) { int t = l; l = lend; lend = t; }
        if (lend > l) {
            // QL iteration
            for (;;) {
                int mq = lend;
                if (l != lend) {
                    for (mq = l; mq <= lend - 1; ++mq) {
                        float tst = fm(RE(mq), RE(mq));
                        if (tst <= fa(fm(fm(eps2, fabsf(RD(mq))), fabsf(RD(mq + 1))), safmin)) break;
                    }
                }
                if (mq < lend) WRE(mq, 0.0f);
                float p = RD(l);
                if (mq == l) { l += 1; if (l <= lend) continue; break; }
                if (mq == l + 1) {
                    float rt1, rt2, cc, ss;
                    if (l == 1) {
                        slaev2_(d1, e1, d2, rt1, rt2, cc, ss);
                        rot2col(z11, z21, z31, z12, z22, z32, cc, ss);
                        d1 = rt1; d2 = rt2; e1 = 0.0f;
                    } else {
                        slaev2_(d2, e2, d3, rt1, rt2, cc, ss);
                        rot2col(z12, z22, z32, z13, z23, z33, cc, ss);
                        d2 = rt1; d3 = rt2; e2 = 0.0f;
                    }
                    l += 2; if (l <= lend) continue; break;
                }
                if (jtot == nmaxit) break;
                jtot++;
                // sweep: reachable only with l==1, mq==3 (|mq-l|>=2 in 1..3)
                float g = fs(d2, p) / fm(2.0f, e1);
                float r = slapy2_(g, 1.0f);
                g = fa(fs(d3, p), e1 / fa(g, fsignf(r, g)));
                float s_ = 1.0f, c_ = 1.0f; p = 0.0f;
                {   // i = 2 (== mq-1: no E(i+1) store)
                    float f = fm(s_, e2), b = fm(c_, e2);
                    slartg_(g, f, c_, s_, r);
                    g = fs(d3, p);
                    r = fa(fm(fs(d2, g), s_), fm(fm(2.0f, c_), b));
                    p = fm(s_, r);
                    d3 = fa(g, p);
                    g = fs(fm(c_, r), b);
                    wc2 = c_; ws2 = -s_;      // QL stores -S
                }
                {   // i = 1: E(2) = r
                    float f = fm(s_, e1), b = fm(c_, e1);
                    slartg_(g, f, c_, s_, r);
                    e2 = r;
                    g = fs(d2, p);
                    r = fa(fm(fs(d1, g), s_), fm(fm(2.0f, c_), b));
                    p = fm(s_, r);
                    d2 = fa(g, p);
                    g = fs(fm(c_, r), b);
                    wc1 = c_; ws1 = -s_;
                }
                rot2col(z12, z22, z32, z13, z23, z33, wc2, ws2);   // rotcf(2,3)
                rot2col(z11, z21, z31, z12, z22, z32, wc1, ws1);   // rotcf(1,2)
                d1 = fs(d1, p); e1 = g;
            }
        } else {
            // QR iteration
            for (;;) {
                int mq = lend;
                if (l != lend) {
                    for (mq = l; mq >= lend + 1; --mq) {
                        float tst = fm(RE(mq - 1), RE(mq - 1));
                        if (tst <= fa(fm(fm(eps2, fabsf(RD(mq))), fabsf(RD(mq - 1))), safmin)) break;
                    }
                }
                if (mq > lend) WRE(mq - 1, 0.0f);
                float p = RD(l);
                if (mq == l) { l -= 1; if (l >= lend) continue; break; }
                if (mq == l - 1) {
                    float rt1, rt2, cc, ss;
                    if (l == 2) {
                        slaev2_(d1, e1, d2, rt1, rt2, cc, ss);
                        rot2col(z11, z21, z31, z12, z22, z32, cc, ss);
                        d1 = rt1; d2 = rt2; e1 = 0.0f;
                    } else {  // l == 3
                        slaev2_(d2, e2, d3, rt1, rt2, cc, ss);
                        rot2col(z12, z22, z32, z13, z23, z33, cc, ss);
                        d2 = rt1; d3 = rt2; e2 = 0.0f;
                    }
                    l -= 2; if (l >= lend) continue; break;
                }
                if (jtot == nmaxit) break;
                jtot++;
                // sweep: reachable only with l==3, mq==1
                float g = fs(d2, p) / fm(2.0f, e2);
                float r = slapy2_(g, 1.0f);
                g = fa(fs(d1, p), e2 / fa(g, fsignf(r, g)));
                float s_ = 1.0f, c_ = 1.0f; p = 0.0f;
                {   // i = 1 (== mq: no E(i-1) store)
                    float f = fm(s_, e1), b = fm(c_, e1);
                    slartg_(g, f, c_, s_, r);
                    g = fs(d1, p);
                    r = fa(fm(fs(d2, g), s_), fm(fm(2.0f, c_), b));
                    p = fm(s_, r);
                    d1 = fa(g, p);
                    g = fs(fm(c_, r), b);
                    wc1 = c_; ws1 = s_;       // QR stores +S
                }
                {   // i = 2: E(1) = r
                    float f = fm(s_, e2), b = fm(c_, e2);
                    slartg_(g, f, c_, s_, r);
                    e1 = r;
                    g = fs(d2, p);
                    r = fa(fm(fs(d3, g), s_), fm(fm(2.0f, c_), b));
                    p = fm(s_, r);
                    d2 = fa(g, p);
                    g = fs(fm(c_, r), b);
                    wc2 = c_; ws2 = s_;
                }
                rot2col(z11, z21, z31, z12, z22, z32, wc1, ws1);   // rotcf(1,2)
                rot2col(z12, z22, z32, z13, z23, z33, wc2, ws2);   // rotcf(2,3)
                d3 = fs(d3, p); e2 = g;
            }
        }
    }
    // ascending selection sort with column swaps (ssteqr tail)
    for (int ii = 2; ii <= 3; ++ii) {
        int i = ii - 1, kk = i; float p = RD(i);
        for (int j = ii; j <= 3; ++j) { float dj = RD(j); if (dj < p) { kk = j; p = dj; } }
        if (kk != i) {
            WRD(kk, RD(i)); WRD(i, p);
            if (i == 1 && kk == 2)      { SWAPC(z11, z12); SWAPC(z21, z22); SWAPC(z31, z32); }
            else if (i == 1 && kk == 3) { SWAPC(z11, z13); SWAPC(z21, z23); SWAPC(z31, z33); }
            else                        { SWAPC(z12, z13); SWAPC(z22, z23); SWAPC(z32, z33); }
        }
    }
    // sormtr: Z := H1 * Z (rows 2..3), slarf/sger op order
    if (tau != 0.0f) {
        float ss, t;
        ss = fa(z21, fm(v3, z31)); t = fm(tau, ss); z21 = fs(z21, t); z31 = fs(z31, fm(t, v3));
        ss = fa(z22, fm(v3, z32)); t = fm(tau, ss); z22 = fs(z22, t); z32 = fs(z32, fm(t, v3));
        ss = fa(z23, fm(v3, z33)); t = fm(tau, ss); z23 = fs(z23, t); z33 = fs(z33, fm(t, v3));
    }
    v1o = z11; v2o = z21; v3o = z31;
}

// ---------------- JAX threefry2x32 (key(42) noise reproduction)
__device__ void threefry2x32_(unsigned k0, unsigned k1, unsigned c0, unsigned c1,
                              unsigned& o0, unsigned& o1) {
    const unsigned rot[8] = {13u, 15u, 26u, 6u, 17u, 29u, 16u, 24u};
    unsigned ks[3] = {k0, k1, k0 ^ k1 ^ 0x1BD11BDAu};
    unsigned x0 = c0 + k0, x1 = c1 + k1;
    for (int blk = 0; blk < 5; ++blk) {
        const unsigned* r = &rot[(blk & 1) * 4];
        for (int i = 0; i < 4; ++i) {
            x0 += x1;
            x1 = (x1 << r[i]) | (x1 >> (32 - r[i]));
            x1 ^= x0;
        }
        x0 += ks[(blk + 1) % 3];
        x1 += ks[(blk + 2) % 3] + (unsigned)(blk + 1);
    }
    o0 = x0; o1 = x1;
}

// noise[j] = (uniform(key(42),(100,3))[j,j] - 0.5) * 1e-8 ; flat idx m = 4*j
__device__ float noise_diag_(int j) {
    unsigned m = (unsigned)(4 * j);
    unsigned o0, o1;
    threefry2x32_(0u, 42u, m, 150u + m, o0, o1);  // m<150 -> first-half output
    unsigned bits = (o0 >> 9) | 0x3f800000u;
    float u = fs(__uint_as_float(bits), 1.0f);    // [0,1)
    return fm(fs(u, 0.5f), 1e-8f);
}

__device__ __forceinline__ float angf(float ax, float ay, float az,
                                      float bx, float by, float bz) {
    float cx = ay * bz - az * by;
    float cy = az * bx - ax * bz;
    float cz = ax * by - ay * bx;
    float cn = sqrtf(cx * cx + cy * cy + cz * cz);
    float d  = ax * bx + ay * by + az * bz;
    return atan2f(cn, d);
}

// ---------------------------------------------------------------- grid build

__global__ void k_prep(const float* __restrict__ pts, float4* __restrict__ pos4,
                       int* __restrict__ pcell, int* __restrict__ hist, int n) {
    int i = blockIdx.x * blockDim.x + threadIdx.x;
    if (i < n) {
        float x = pts[i * 3], y = pts[i * 3 + 1], z = pts[i * 3 + 2];
        float sq = fa(fa(fm(x, x), fm(y, y)), fm(z, z));
        pos4[i] = make_float4(x, y, z, sq);
        int cx = (int)(x * 8.0f); cx = cx < 0 ? 0 : (cx > GRD - 1 ? GRD - 1 : cx);
        int cy = (int)(y * 8.0f); cy = cy < 0 ? 0 : (cy > GRD - 1 ? GRD - 1 : cy);
        int cz = (int)(z * 8.0f); cz = cz < 0 ? 0 : (cz > GRD - 1 ? GRD - 1 : cz);
        int cid = (cz * GRD + cy) * GRD + cx;
        pcell[i] = cid;
        atomicAdd(&hist[cid], 1);
    }
}

// single block, NCELL threads: exclusive scan of hist -> start[0..NCELL], cursor copy
__global__ __launch_bounds__(NCELL) void k_scan(const int* __restrict__ hist,
                                                int* __restrict__ start,
                                                int* __restrict__ cursor) {
    __shared__ int s[NCELL];
    int t = threadIdx.x;
    int v = hist[t];
    s[t] = v;
    __syncthreads();
    for (int off = 1; off < NCELL; off <<= 1) {
        int x = (t >= off) ? s[t - off] : 0;
        __syncthreads();
        s[t] += x;
        __syncthreads();
    }
    int ex = s[t] - v;
    start[t] = ex;
    cursor[t] = ex;
    if (t == NCELL - 1) start[NCELL] = s[t];
}

__global__ void k_scatter(const int* __restrict__ pcell, int* __restrict__ cursor,
                          int* __restrict__ order, int n) {
    int i = blockIdx.x * blockDim.x + threadIdx.x;
    if (i < n) {
        int slot = atomicAdd(&cursor[pcell[i]], 1);
        order[slot] = i;
    }
}

// ---------------------------------------------------------------- grid KNN
#define KEY_WORST 0xC0001FFFFFFFFFFFull
#define CBUF 128

__global__ __launch_bounds__(256) void k_knn(const float4* __restrict__ pos4,
                                             const int* __restrict__ order,
                                             const int* __restrict__ cstart,
                                             int* __restrict__ cols, int n) {
    __shared__ unsigned long long sbuf[4][CBUF];
    __shared__ int scnt[4];

    int lane = threadIdx.x & 63;
    int wv = threadIdx.x >> 6;
    int io = blockIdx.x * 4 + wv;
    if (io >= n) return;   // no block-wide barriers below: per-wave exit is safe

    float4 P = pos4[io];
    int cx = (int)(P.x * 8.0f); cx = cx < 0 ? 0 : (cx > GRD - 1 ? GRD - 1 : cx);
    int cy = (int)(P.y * 8.0f); cy = cy < 0 ? 0 : (cy > GRD - 1 ? GRD - 1 : cy);
    int cz = (int)(P.z * 8.0f); cz = cz < 0 ? 0 : (cz > GRD - 1 ? GRD - 1 : cz);

    unsigned T = 0xFFFFFFFFu;
    int xlo = 0, xhi = 0, ylo = 0, yhi = 0, zlo = 0, zhi = 0;

    for (int r = 1; r < 16; ++r) {
        xlo = cx - r; if (xlo < 0) xlo = 0;
        xhi = cx + r; if (xhi > GRD - 1) xhi = GRD - 1;
        ylo = cy - r; if (ylo < 0) ylo = 0;
        yhi = cy + r; if (yhi > GRD - 1) yhi = GRD - 1;
        zlo = cz - r; if (zlo < 0) zlo = 0;
        zhi = cz + r; if (zhi > GRD - 1) zhi = GRD - 1;

        // ---- pass 1: per-lane top-2 raw-bit d2 over the cell block
        unsigned b0 = 0xFFFFFFFFu, b1 = 0xFFFFFFFFu;
        for (int zz = zlo; zz <= zhi; ++zz)
            for (int yy = ylo; yy <= yhi; ++yy) {
                int rowb = (zz * GRD + yy) * GRD;   // x-cells contiguous
                int jb = cstart[rowb + xlo];
                int je = cstart[rowb + xhi + 1];
                for (int t = jb + lane; t < je; t += 64) {
                    int j = order[t];
                    float4 Q = pos4[j];
                    float g = fm(P.x, Q.x);
                    g = fmaf(P.y, Q.y, g);
                    g = fmaf(P.z, Q.z, g);
                    float d2 = fs(fa(P.w, Q.w), fm(2.0f, g));
                    unsigned u = __float_as_uint(d2);
                    u = (j == io) ? 0xFFFFFFFFu : u;
                    unsigned lo = umin32(b0, u);
                    unsigned hi = umax32(b0, u);
                    b0 = lo;
                    b1 = umin32(b1, hi);
                }
            }

        // ---- 13th smallest of per-lane top-2 union: upper bound on true 13th
        {
            unsigned h0 = b0, h1 = b1;
            T = 0xFFFFFFFFu;
            for (int rr = 0; rr < KNB + 1; ++rr) {
                unsigned mn = h0;
#pragma unroll
                for (int off = 32; off >= 1; off >>= 1) {
                    unsigned o = (unsigned)__shfl_xor((int)mn, off, 64);
                    mn = umin32(mn, o);
                }
                unsigned long long bl = __ballot(h0 == mn);
                int first = __ffsll(bl) - 1;
                if (lane == first) { h0 = h1; h1 = 0xFFFFFFFFu; }
                T = mn;
            }
        }

        // ---- sufficiency: all true top-12 inside the searched block?
        bool cover = (xlo == 0) && (xhi == GRD - 1) && (ylo == 0) && (yhi == GRD - 1)
                  && (zlo == 0) && (zhi == GRD - 1);
        if (cover) break;
        if (T != 0xFFFFFFFFu) {
            // distance from P to nearest in-cube face of the searched block
            float gmin = 1e30f;
            if (xlo > 0)       gmin = fminf(gmin, fs(P.x, (float)xlo * 0.125f));
            if (xhi < GRD - 1) gmin = fminf(gmin, fs((float)(xhi + 1) * 0.125f, P.x));
            if (ylo > 0)       gmin = fminf(gmin, fs(P.y, (float)ylo * 0.125f));
            if (yhi < GRD - 1) gmin = fminf(gmin, fs((float)(yhi + 1) * 0.125f, P.y));
            if (zlo > 0)       gmin = fminf(gmin, fs(P.z, (float)zlo * 0.125f));
            if (zhi < GRD - 1) gmin = fminf(gmin, fs((float)(zhi + 1) * 0.125f, P.z));
            float g2 = fm(fm(gmin, gmin), 0.9995f);   // margin >> f32 rounding
            if (__uint_as_float(T) <= g2) break;
        }
        // else: expand ring (rare: anomalously sparse neighborhoods)
    }

    // ---- pass 2: compact candidates with raw bits <= T into the wave buffer
    if (lane == 0) scnt[wv] = 0;
    __builtin_amdgcn_wave_barrier();
    for (int zz = zlo; zz <= zhi; ++zz)
        for (int yy = ylo; yy <= yhi; ++yy) {
            int rowb = (zz * GRD + yy) * GRD;
            int jb = cstart[rowb + xlo];
            int je = cstart[rowb + xhi + 1];
            for (int t = jb + lane; t < je; t += 64) {
                int j = order[t];
                float4 Q = pos4[j];
                float g = fm(P.x, Q.x);
                g = fmaf(P.y, Q.y, g);
                g = fmaf(P.z, Q.z, g);
                float d2 = fs(fa(P.w, Q.w), fm(2.0f, g));
                unsigned u = __float_as_uint(d2);
                bool c = (u <= T) && (j != io);
                unsigned long long bl = __ballot(c);
                if (bl) {
                    int leader = __ffsll(bl) - 1;
                    int base = 0;
                    if (lane == leader)
                        base = atomicAdd(&scnt[wv], (int)__popcll(bl));
                    base = __shfl(base, leader, 64);
                    if (c) {
                        int pos = base + (int)__popcll(bl & ((1ull << lane) - 1ull));
                        unsigned us = u ^ (unsigned)(((int)u >> 31) | 0x80000000);
                        unsigned long long kb = (((unsigned long long)us << 13) | (unsigned)j)
                                                | 0xC000000000000000ull;
                        if (pos < CBUF) sbuf[wv][pos] = kb;
                    }
                }
            }
        }
    __builtin_amdgcn_wave_barrier();
    int cnt = scnt[wv];
    if (cnt > CBUF) cnt = CBUF;

    // ---- exact top-12 from buffer (packed keys as negative doubles: fmax = min-key)
    double k0 = __longlong_as_double((long long)KEY_WORST);
    double k1 = __longlong_as_double((long long)KEY_WORST);
    if (lane < cnt) k0 = __longlong_as_double((long long)sbuf[wv][lane]);
    if (lane + 64 < cnt) k1 = __longlong_as_double((long long)sbuf[wv][lane + 64]);
    double mykey = __longlong_as_double((long long)KEY_WORST);
    for (int rr = 0; rr < KNB; ++rr) {
        double mx = fmax(k0, k1);
#pragma unroll
        for (int off = 32; off >= 1; off >>= 1)
            mx = fmax(mx, __shfl_xor(mx, off, 64));
        if (k0 == mx) k0 = __longlong_as_double((long long)KEY_WORST);
        else if (k1 == mx) k1 = __longlong_as_double((long long)KEY_WORST);
        if (lane == rr) mykey = mx;
    }
    if (lane < KNB) {
        unsigned long long bits = (unsigned long long)__double_as_longlong(mykey);
        unsigned j = (unsigned)(bits & 0x1FFFu);
        unsigned u = (unsigned)((bits >> 13) & 0xFFFFFFFFull);
        unsigned ob = (u & 0x80000000u) ? (u ^ 0x80000000u) : ~u;
        float d2 = __uint_as_float(ob);
        cols[io * KNB + lane] = (d2 <= 0.25f) ? (int)j : io;
    }
}

// ---------------------------------------------------------------- normals
__global__ __launch_bounds__(64) void k_normals(const float4* __restrict__ pos4,
                                                const int* __restrict__ cols,
                                                float4* __restrict__ nrm4,
                                                float* __restrict__ out, int n) {
    int i = blockIdx.x * blockDim.x + threadIdx.x;
    if (i >= n) return;

    float qx[KNB], qy[KNB], qz[KNB];
#pragma unroll
    for (int k = 0; k < KNB; ++k) {
        float4 q = pos4[cols[i * KNB + k]];
        qx[k] = q.x; qy[k] = q.y; qz[k] = q.z;
    }
    // mean: f32 sequential over k
    float sx = qx[0], sy = qy[0], sz = qz[0];
#pragma unroll
    for (int k = 1; k < KNB; ++k) { sx = fa(sx, qx[k]); sy = fa(sy, qy[k]); sz = fa(sz, qz[k]); }
    float mx = sx / 12.0f, my = sy / 12.0f, mz = sz / 12.0f;
    // cov: f32 sequential over k (np.einsum order)
    float c00 = 0, c10 = 0, c20 = 0, c11 = 0, c21 = 0, c22 = 0;
#pragma unroll
    for (int k = 0; k < KNB; ++k) {
        float dx = fs(qx[k], mx), dy = fs(qy[k], my), dz = fs(qz[k], mz);
        c00 = fa(c00, fm(dx, dx));
        c10 = fa(c10, fm(dy, dx));
        c20 = fa(c20, fm(dz, dx));
        c11 = fa(c11, fm(dy, dy));
        c21 = fa(c21, fm(dz, dy));
        c22 = fa(c22, fm(dz, dz));
    }
    c00 = c00 / 12.0f; c10 = c10 / 12.0f; c20 = c20 / 12.0f;
    c11 = c11 / 12.0f; c21 = c21 / 12.0f; c22 = c22 / 12.0f;
    // + jnp.diag(noise): np eigh reads lower, A[i][j] += v[j]
    float v0 = noise_diag_(0), v1 = noise_diag_(1), v2 = noise_diag_(2);
    float a00 = fa(c00, v0), a10 = fa(c10, v0), a20 = fa(c20, v0);
    float a11 = fa(c11, v1), a21 = fa(c21, v1), a22 = fa(c22, v2);
    float e1, e2, e3;
    eig3_smallest_reg(a00, a10, a20, a11, a21, a22, e1, e2, e3);
    nrm4[i] = make_float4(e1, e2, e3, 0.0f);
    out[i]         = e1;
    out[n + i]     = e2;
    out[2 * n + i] = e3;
}

// ---------------------------------------------------------------- MLP chain
// 24 threads/point: 12 edges x 2 hidden-halves. l-MLPs split across halves
// (LDS partial reduce); g-MLPs distribute 32 hidden units across 24 lanes.
// All LDS strides odd (17/13) -> conflict-free.
// NOTE: hidden loops deliberately NOT #pragma unroll'd -- full unroll caused
// register spills (R3: WRITE_SIZE 39.8MB/dispatch scratch traffic, -44 us).

struct WPtrs { const float* p[28]; };

// half of an l-MLP: this thread computes hidden units [hf*NH/2, (hf+1)*NH/2)
template <int NI, int NH, int NO>
__device__ __forceinline__ void mlp_half(const float* __restrict__ w1, const float* __restrict__ b1,
                                         const float* __restrict__ w2, const float* __restrict__ b2,
                                         const float* in, float* out, int hf) {
#pragma unroll
    for (int o = 0; o < NO; ++o) out[o] = hf ? 0.0f : b2[o];
    const int HH = NH / 2;
    int h0 = hf * HH;
    for (int hi = 0; hi < HH; ++hi) {   // no unroll: avoids VGPR spill
        int h = h0 + hi;
        float hh = b1[h];
#pragma unroll
        for (int ii = 0; ii < NI; ++ii) hh = fmaf(in[ii], w1[ii * NH + h], hh);
        hh = fmaxf(hh, 0.0f);
#pragma unroll
        for (int o = 0; o < NO; ++o) out[o] = fmaf(hh, w2[h * NO + o], out[o]);
    }
}

// g-MLP (NH=32) partial: thread q handles h=q, plus h=24+q when q<8.
template <int NI, int NO>
__device__ __forceinline__ void gmlp_part(const float* __restrict__ w1, const float* __restrict__ b1,
                                          const float* __restrict__ w2, const float* __restrict__ b2,
                                          const float* in, float* pout, int q) {
#pragma unroll
    for (int o = 0; o < NO; ++o) pout[o] = (q == 0) ? b2[o] : 0.0f;
    {
        float hh = b1[q];
#pragma unroll
        for (int ii = 0; ii < NI; ++ii) hh = fmaf(in[ii], w1[ii * 32 + q], hh);
        hh = fmaxf(hh, 0.0f);
#pragma unroll
        for (int o = 0; o < NO; ++o) pout[o] = fmaf(hh, w2[q * NO + o], pout[o]);
    }
    if (q < 8) {
        int h = 24 + q;
        float hh = b1[h];
#pragma unroll
        for (int ii = 0; ii < NI; ++ii) hh = fmaf(in[ii], w1[ii * 32 + h], hh);
        hh = fmaxf(hh, 0.0f);
#pragma unroll
        for (int o = 0; o < NO; ++o) pout[o] = fmaf(hh, w2[h * NO + o], pout[o]);
    }
}

#define SCR(pp, qq, oo) s_scr[((pp) * 24 + (qq)) * 17 + (oo)]
#define SX(pp, kk, oo)  s_x[((pp) * 12 + (kk)) * 17 + (oo)]
#define SM(pp, oo)      s_m[(pp) * 17 + (oo)]
#define GFV(pp, oo)     s_g[(pp) * 13 + (oo)]
#define SLG(pp, kk)     s_log[(pp) * 13 + (kk)]

__global__ __launch_bounds__(384) void k_mlp(const float4* __restrict__ pos4,
                                             const int* __restrict__ cols,
                                             const float4* __restrict__ nrm4,
                                             WPtrs wp, float* __restrict__ out, int n) {
    __shared__ float s_scr[16 * 24 * 17];   // partial buffers (l-halves / g-lanes)
    __shared__ float s_x[16 * 12 * 17];     // per-edge x (for means)
    __shared__ float s_m[16 * 17];          // per-point means
    __shared__ float s_g[16 * 13];          // g-MLP outputs
    __shared__ float s_log[16 * 13];        // logits
    __shared__ float s_red[16 * 2];         // softmax max/sum

    int t = threadIdx.x;
    int p = t / 24, q = t - p * 24;
    int k = q % 12, hf = q / 12;
    int nn = blockIdx.x * 16 + p;
    bool act = (nn < n);

    float cx = 0, cy = 0, cz = 0, nrx = 0, nry = 0, nrz = 0;
    float xr[16];

    // ---- stage A: edge features + l1 (half)
    if (act) {
        int col = cols[nn * 12 + k];
        float4 P = pos4[nn], Q = pos4[col];
        cx = Q.x - P.x; cy = Q.y - P.y; cz = Q.z - P.z;
        float dist = sqrtf(cx * cx + cy * cy + cz * cz);
        float4 NR = nrm4[nn], NC = nrm4[col];
        nrx = NR.x; nry = NR.y; nrz = NR.z;
        float a1 = angf(nrx, nry, nrz, cx, cy, cz);
        float a2 = angf(NC.x, NC.y, NC.z, cx, cy, cz);
        float a3 = angf(nrx, nry, nrz, NC.x, NC.y, NC.z);
        float in7[7] = {cx, cy, cz, dist, a1, a2, a3};
        float px[16];
        mlp_half<7, 32, 16>(wp.p[0], wp.p[1], wp.p[2], wp.p[3], in7, px, hf);
#pragma unroll
        for (int o = 0; o < 16; ++o) SCR(p, q, o) = px[o];
    }
    __syncthreads();
    if (act) {
#pragma unroll
        for (int o = 0; o < 16; ++o) xr[o] = SCR(p, k, o) + SCR(p, 12 + k, o);
        if (hf == 0)
#pragma unroll
            for (int o = 0; o < 16; ++o) SX(p, k, o) = xr[o];
    }
    __syncthreads();

    // ---- stage B: mean + g1 (lane-parallel)
    if (act && q < 16) {
        float s = 0.0f;
        for (int kk = 0; kk < 12; ++kk) s += SX(p, kk, q);
        SM(p, q) = s / 12.0f;
    }
    __syncthreads();
    if (act) {
        float gin[19];
#pragma unroll
        for (int ii = 0; ii < 16; ++ii) gin[ii] = SM(p, ii);
        gin[16] = nrx; gin[17] = nry; gin[18] = nrz;
        float pg[8];
        gmlp_part<19, 8>(wp.p[4], wp.p[5], wp.p[6], wp.p[7], gin, pg, q);
#pragma unroll
        for (int o = 0; o < 8; ++o) SCR(p, q, o) = pg[o];
    }
    __syncthreads();
    if (act && q < 8) {
        float s = 0.0f;
        for (int j = 0; j < 24; ++j) s += SCR(p, j, q);
        GFV(p, q) = s;
    }
    __syncthreads();

    // ---- stage C: l2 (half)
    if (act) {
        float in24[24];
#pragma unroll
        for (int o = 0; o < 16; ++o) in24[o] = xr[o];
#pragma unroll
        for (int o = 0; o < 8; ++o) in24[16 + o] = GFV(p, o);
        float px[16];
        mlp_half<24, 32, 16>(wp.p[8], wp.p[9], wp.p[10], wp.p[11], in24, px, hf);
#pragma unroll
        for (int o = 0; o < 16; ++o) SCR(p, q, o) = px[o];
    }
    __syncthreads();
    if (act) {
#pragma unroll
        for (int o = 0; o < 16; ++o) xr[o] = SCR(p, k, o) + SCR(p, 12 + k, o);
        if (hf == 0)
#pragma unroll
            for (int o = 0; o < 16; ++o) SX(p, k, o) = xr[o];
    }
    __syncthreads();

    // ---- stage D: mean + g2
    if (act && q < 16) {
        float s = 0.0f;
        for (int kk = 0; kk < 12; ++kk) s += SX(p, kk, q);
        SM(p, q) = s / 12.0f;
    }
    __syncthreads();
    if (act) {
        float gin[16];
#pragma unroll
        for (int ii = 0; ii < 16; ++ii) gin[ii] = SM(p, ii);
        float pg[8];
        gmlp_part<16, 8>(wp.p[12], wp.p[13], wp.p[14], wp.p[15], gin, pg, q);
#pragma unroll
        for (int o = 0; o < 8; ++o) SCR(p, q, o) = pg[o];
    }
    __syncthreads();
    if (act && q < 8) {
        float s = 0.0f;
        for (int j = 0; j < 24; ++j) s += SCR(p, j, q);
        GFV(p, q) = s;
    }
    __syncthreads();

    // ---- stage E: l3 (half)
    if (act) {
        float in24[24];
#pragma unroll
        for (int o = 0; o < 16; ++o) in24[o] = xr[o];
#pragma unroll
        for (int o = 0; o < 8; ++o) in24[16 + o] = GFV(p, o);
        float px[16];
        mlp_half<24, 32, 16>(wp.p[16], wp.p[17], wp.p[18], wp.p[19], in24, px, hf);
#pragma unroll
        for (int o = 0; o < 16; ++o) SCR(p, q, o) = px[o];
    }
    __syncthreads();
    if (act) {
#pragma unroll
        for (int o = 0; o < 16; ++o) xr[o] = SCR(p, k, o) + SCR(p, 12 + k, o);
        if (hf == 0)
#pragma unroll
            for (int o = 0; o < 16; ++o) SX(p, k, o) = xr[o];
    }
    __syncthreads();

    // ---- stage F: mean + g3 (12 outputs)
    if (act && q < 16) {
        float s = 0.0f;
        for (int kk = 0; kk < 12; ++kk) s += SX(p, kk, q);
        SM(p, q) = s / 12.0f;
    }
    __syncthreads();
    if (act) {
        float gin[16];
#pragma unroll
        for (int ii = 0; ii < 16; ++ii) gin[ii] = SM(p, ii);
        float pg[12];
        gmlp_part<16, 12>(wp.p[20], wp.p[21], wp.p[22], wp.p[23], gin, pg, q);
#pragma unroll
        for (int o = 0; o < 12; ++o) SCR(p, q, o) = pg[o];
    }
    __syncthreads();
    if (act && q < 12) {
        float s = 0.0f;
        for (int j = 0; j < 24; ++j) s += SCR(p, j, q);
        GFV(p, q) = s;
    }
    __syncthreads();

    // ---- stage G: quat->mat (computed redundantly per thread) + l4 (half)
    if (act) {
        float g0 = GFV(p, 0), g1v = GFV(p, 1), g2v = GFV(p, 2), g3v = GFV(p, 3);
        float qn = sqrtf(g0 * g0 + g1v * g1v + g2v * g2v + g3v * g3v) + 1e-8f;
        float qw = g0 / qn, qxx = g1v / qn, qyy = g2v / qn, qzz = g3v / qn;
        float m0 = 1.0f - 2.0f * (qyy * qyy + qzz * qzz);
        float m1 = 2.0f * (qxx * qyy - qzz * qw);
        float m2 = 2.0f * (qxx * qzz + qyy * qw);
        float m3 = 2.0f * (qxx * qyy + qzz * qw);
        float m4 = 1.0f - 2.0f * (qxx * qxx + qzz * qzz);
        float m5 = 2.0f * (qyy * qzz - qxx * qw);
        float m6 = 2.0f * (qxx * qzz - qyy * qw);
        float m7 = 2.0f * (qyy * qzz + qxx * qw);
        float m8 = 1.0f - 2.0f * (qxx * qxx + qyy * qyy);
        float r0 = m0 * cx + m1 * cy + m2 * cz;
        float r1 = m3 * cx + m4 * cy + m5 * cz;
        float r2 = m6 * cx + m7 * cy + m8 * cz;
        float in27[27];
#pragma unroll
        for (int o = 0; o < 16; ++o) in27[o] = xr[o];
#pragma unroll
        for (int o = 0; o < 8; ++o) in27[16 + o] = GFV(p, 4 + o);
        in27[24] = r0; in27[25] = r1; in27[26] = r2;
        float plg[1];
        mlp_half<27, 64, 1>(wp.p[24], wp.p[25], wp.p[26], wp.p[27], in27, plg, hf);
        SCR(p, q, 0) = plg[0];
    }
    __syncthreads();
    if (act && hf == 0) SLG(p, k) = SCR(p, k, 0) + SCR(p, 12 + k, 0);
    __syncthreads();

    // ---- stage H: softmax over the 12 edges (same op order as reference)
    if (act && q == 0) {
        float mx = SLG(p, 0);
        for (int kk = 1; kk < 12; ++kk) mx = fmaxf(mx, SLG(p, kk));
        float se = 0;
        for (int kk = 0; kk < 12; ++kk) se += expf(SLG(p, kk) - mx);
        s_red[p * 2] = mx; s_red[p * 2 + 1] = se;
    }
    __syncthreads();
    if (act && hf == 0) {
        float v = expf(SLG(p, k) - s_red[p * 2]) / s_red[p * 2 + 1];
        out[3 * n + k * n + nn] = v;
    }
}

// ---------------------------------------------------------------- launch

extern "C" void kernel_launch(void* const* d_in, const int* in_sizes, int n_in,
                              void* d_out, int out_size, void* d_ws, size_t ws_size,
                              hipStream_t stream) {
    const float* pts = (const float*)d_in[0];
    int n = in_sizes[0] / 3;

    char* ws = (char*)d_ws;
    float4* pos4  = (float4*)ws;                            // n*16 B
    int*    cols  = (int*)(ws + (size_t)n * 16);            // n*48 B
    float4* nrm4  = (float4*)(ws + (size_t)n * 64);         // n*16 B
    int*    pcell = (int*)(ws + (size_t)n * 80);            // n*4 B
    int*    order = (int*)(ws + (size_t)n * 84);            // n*4 B
    int*    hist  = (int*)(ws + (size_t)n * 88);            // NCELL ints
    int*    start = hist + NCELL;                           // NCELL+1 ints
    int*    cursor = start + NCELL + 1;                     // NCELL ints
    float*  out = (float*)d_out;

    WPtrs wp;
    for (int a = 0; a < 28; ++a) wp.p[a] = (const float*)d_in[a + 1];

    hipMemsetAsync(hist, 0, NCELL * sizeof(int), stream);   // replaces k_zero
    k_prep<<<(n + 255) / 256, 256, 0, stream>>>(pts, pos4, pcell, hist, n);
    k_scan<<<1, NCELL, 0, stream>>>(hist, start, cursor);
    k_scatter<<<(n + 255) / 256, 256, 0, stream>>>(pcell, cursor, order, n);
    k_knn<<<(n + 3) / 4, 256, 0, stream>>>(pos4, order, start, cols, n);
    k_normals<<<(n + 63) / 64, 64, 0, stream>>>(pos4, cols, nrm4, out, n);
    // 24 threads/point (12 edges x 2 hidden-halves), 16 points/block
    k_mlp<<<(n + 15) / 16, 384, 0, stream>>>(pos4, cols, nrm4, wp, out, n);
}

// Round 5
// 207.660 us; speedup vs baseline: 1.3813x; 1.2252x over previous
//
#include <hip/hip_runtime.h>
#include <math.h>

#define KNB 12
#define GRD 8
#define NCELL (GRD * GRD * GRD)   // 512 cells, cell edge = 0.125

// ---------------------------------------------------------------- helpers

__device__ __forceinline__ unsigned umin32(unsigned a, unsigned b) {
    unsigned r; asm("v_min_u32 %0, %1, %2" : "=v"(r) : "v"(a), "v"(b)); return r;
}
__device__ __forceinline__ unsigned umax32(unsigned a, unsigned b) {
    unsigned r; asm("v_max_u32 %0, %1, %2" : "=v"(r) : "v"(a), "v"(b)); return r;
}

// ---------------- f32 no-contract primitives (match CPU netlib rounding)
__device__ __forceinline__ float fm(float a, float b) { return __fmul_rn(a, b); }
__device__ __forceinline__ float fa(float a, float b) { return __fadd_rn(a, b); }
__device__ __forceinline__ float fs(float a, float b) { return __fsub_rn(a, b); }
__device__ __forceinline__ float fsignf(float a, float b) { return (b >= 0.0f) ? fabsf(a) : -fabsf(a); }

__device__ float slapy2_(float x, float y) {
    float xa = fabsf(x), ya = fabsf(y);
    float w = fmaxf(xa, ya), z = fminf(xa, ya);
    if (z == 0.0f) return w;
    float q = z / w;
    return fm(w, __fsqrt_rn(fa(1.0f, fm(q, q))));
}

// LAPACK >=3.10 slartg: c = |f|/d >= 0, r = sign(f)*d
__device__ void slartg_(float f, float g, float& c, float& s, float& r) {
    if (g == 0.0f) { c = 1.0f; s = 0.0f; r = f; }
    else if (f == 0.0f) { c = 0.0f; s = (g >= 0.0f) ? 1.0f : -1.0f; r = fabsf(g); }
    else {
        float d = __fsqrt_rn(fa(fm(f, f), fm(g, g)));
        c = fabsf(f) / d;
        r = (f >= 0.0f) ? d : -d;
        s = g / r;
    }
}

// netlib slaev2 (f32): eigvec of RT1 is (cs1, sn1)
__device__ void slaev2_(float a, float b, float cc,
                        float& rt1, float& rt2, float& cs1, float& sn1) {
    float sm = fa(a, cc), df = fs(a, cc), adf = fabsf(df);
    float tb = fa(b, b), ab = fabsf(tb);
    float acmx, acmn;
    if (fabsf(a) > fabsf(cc)) { acmx = a; acmn = cc; } else { acmx = cc; acmn = a; }
    float rt;
    if (adf > ab)      { float q = ab / adf; rt = fm(adf, __fsqrt_rn(fa(1.0f, fm(q, q)))); }
    else if (adf < ab) { float q = adf / ab; rt = fm(ab,  __fsqrt_rn(fa(1.0f, fm(q, q)))); }
    else               rt = fm(ab, __fsqrt_rn(2.0f));
    int sgn1;
    if (sm < 0.0f) {
        rt1 = fm(0.5f, fs(sm, rt)); sgn1 = -1;
        rt2 = fs(fm(acmx / rt1, acmn), fm(b / rt1, b));
    } else if (sm > 0.0f) {
        rt1 = fm(0.5f, fa(sm, rt)); sgn1 = 1;
        rt2 = fs(fm(acmx / rt1, acmn), fm(b / rt1, b));
    } else { rt1 = fm(0.5f, rt); rt2 = fm(-0.5f, rt); sgn1 = 1; }
    int sgn2; float cs;
    if (df >= 0.0f) { cs = fa(df, rt); sgn2 = 1; } else { cs = fs(df, rt); sgn2 = -1; }
    float acs = fabsf(cs);
    if (acs > ab) {
        float ct = -tb / cs;
        sn1 = 1.0f / __fsqrt_rn(fa(1.0f, fm(ct, ct)));
        cs1 = fm(ct, sn1);
    } else {
        if (ab == 0.0f) { cs1 = 1.0f; sn1 = 0.0f; }
        else {
            float tn = -cs / tb;
            cs1 = 1.0f / __fsqrt_rn(fa(1.0f, fm(tn, tn)));
            sn1 = fm(tn, cs1);
        }
    }
    if (sgn1 == sgn2) { float tn = cs1; cs1 = -sn1; sn1 = tn; }
}

// slasr single rotation on Z columns (j1,j2): a* = col j1, b* = col j2.
// Literal netlib expression order.
__device__ __forceinline__ void rot2col(float& a1, float& a2, float& a3,
                                        float& b1, float& b2, float& b3,
                                        float ct, float st) {
    float t;
    t = b1; b1 = fs(fm(ct, t), fm(st, a1)); a1 = fa(fm(st, t), fm(ct, a1));
    t = b2; b2 = fs(fm(ct, t), fm(st, a2)); a2 = fa(fm(st, t), fm(ct, a2));
    t = b3; b3 = fs(fm(ct, t), fm(st, a3)); a3 = fa(fm(st, t), fm(ct, a3));
}

// dynamic-index accessors over NAMED registers (cndmask selects, no memory).
#define RD(i)    ((i) == 1 ? d1 : ((i) == 2 ? d2 : d3))
#define WRD(i,v) do { float _t = (v); if ((i) == 1) d1 = _t; else if ((i) == 2) d2 = _t; else d3 = _t; } while (0)
#define RE(i)    ((i) == 1 ? e1 : e2)
#define WRE(i,v) do { float _t = (v); if ((i) == 1) e1 = _t; else e2 = _t; } while (0)
#define SWAPC(a,b) do { float _t = (a); (a) = (b); (b) = _t; } while (0)

// Faithful f32 port of ssyevd path (ssytd2 'L' -> ssteqr 'I' -> sormtr) for a
// 3x3 symmetric-lower matrix; eigvec of smallest eigenvalue, LAPACK signs.
// Pure-register storage: identical op sequence to the LDS version (bit-equal).
__device__ void eig3_smallest_reg(float a00, float a10, float a20,
                                  float a11, float a21, float a22,
                                  float& v1o, float& v2o, float& v3o) {
    float z11 = 1.0f, z21 = 0.0f, z31 = 0.0f;
    float z12 = 0.0f, z22 = 1.0f, z32 = 0.0f;
    float z13 = 0.0f, z23 = 0.0f, z33 = 1.0f;
    float d1, d2, d3, e1, e2;
    float wc1 = 0.0f, wc2 = 0.0f, ws1 = 0.0f, ws2 = 0.0f;

    // --- ssytd2 'L' (single Householder on column 1), faithful BLAS op order
    float tau = 0.0f, v3 = 0.0f;
    d1 = a00;
    if (a20 != 0.0f) {
        float xn = fabsf(a20);                      // snrm2 length-1
        float beta = -fsignf(slapy2_(a10, xn), a10);
        tau = fs(beta, a10) / beta;
        float rinv = 1.0f / fs(a10, beta);          // sscal: recip then mul
        v3 = fm(a20, rinv);
        e1 = beta;
        // ssymv lower n=2: w = tau * A22 * (1, v3)
        float w1 = fa(fm(tau, a11), fm(tau, fm(a21, v3)));
        float w2 = fa(fm(tau, a21), fm(fm(tau, v3), a22));
        float dot = fa(w1, fm(w2, v3));
        float al = fm(fm(-0.5f, tau), dot);
        w1 = fa(w1, al);
        w2 = fa(w2, fm(al, v3));
        d2 = fs(fs(a11, w1), w1);
        e2 = fs(fs(a21, fm(v3, w1)), w2);
        d3 = fs(fs(a22, fm(v3, w2)), fm(w2, v3));
    } else {
        e1 = a10; d2 = a11; e2 = a21; d3 = a22;
    }

    // --- ssteqr 'I' (f32 constants)
    const float eps = 5.9604645e-8f;        // slamch('E') = 2^-24
    const float eps2 = 3.5527137e-15f;      // eps^2
    const float safmin = 1.17549435e-38f;   // slamch('S')
    int jtot = 0; const int nmaxit = 90;
    int l1 = 1;
    while (l1 <= 3) {
        if (l1 > 1) WRE(l1 - 1, 0.0f);
        int m;
        for (m = l1; m <= 2; ++m) {
            float tst = fabsf(RE(m));
            if (tst == 0.0f) break;
            if (tst <= fm(fm(__fsqrt_rn(fabsf(RD(m))), __fsqrt_rn(fabsf(RD(m + 1)))), eps)) {
                WRE(m, 0.0f); break;
            }
        }
        int l = l1, lend = m;
        l1 = m + 1;
        if (lend == l) continue;
        if (fabsf(RD(lend)) < fabsf(RD(l))) { int t = l; l = lend; lend = t; }
        if (lend > l) {
            // QL iteration
            for (;;) {
                int mq = lend;
                if (l != lend) {
                    for (mq = l; mq <= lend - 1; ++mq) {
                        float tst = fm(RE(mq), RE(mq));
                        if (tst <= fa(fm(fm(eps2, fabsf(RD(mq))), fabsf(RD(mq + 1))), safmin)) break;
                    }
                }
                if (mq < lend) WRE(mq, 0.0f);
                float p = RD(l);
                if (mq == l) { l += 1; if (l <= lend) continue; break; }
                if (mq == l + 1) {
                    float rt1, rt2, cc, ss;
                    if (l == 1) {
                        slaev2_(d1, e1, d2, rt1, rt2, cc, ss);
                        rot2col(z11, z21, z31, z12, z22, z32, cc, ss);
                        d1 = rt1; d2 = rt2; e1 = 0.0f;
                    } else {
                        slaev2_(d2, e2, d3, rt1, rt2, cc, ss);
                        rot2col(z12, z22, z32, z13, z23, z33, cc, ss);
                        d2 = rt1; d3 = rt2; e2 = 0.0f;
                    }
                    l += 2; if (l <= lend) continue; break;
                }
                if (jtot == nmaxit) break;
                jtot++;
                // sweep: reachable only with l==1, mq==3 (|mq-l|>=2 in 1..3)
                float g = fs(d2, p) / fm(2.0f, e1);
                float r = slapy2_(g, 1.0f);
                g = fa(fs(d3, p), e1 / fa(g, fsignf(r, g)));
                float s_ = 1.0f, c_ = 1.0f; p = 0.0f;
                {   // i = 2 (== mq-1: no E(i+1) store)
                    float f = fm(s_, e2), b = fm(c_, e2);
                    slartg_(g, f, c_, s_, r);
                    g = fs(d3, p);
                    r = fa(fm(fs(d2, g), s_), fm(fm(2.0f, c_), b));
                    p = fm(s_, r);
                    d3 = fa(g, p);
                    g = fs(fm(c_, r), b);
                    wc2 = c_; ws2 = -s_;      // QL stores -S
                }
                {   // i = 1: E(2) = r
                    float f = fm(s_, e1), b = fm(c_, e1);
                    slartg_(g, f, c_, s_, r);
                    e2 = r;
                    g = fs(d2, p);
                    r = fa(fm(fs(d1, g), s_), fm(fm(2.0f, c_), b));
                    p = fm(s_, r);
                    d2 = fa(g, p);
                    g = fs(fm(c_, r), b);
                    wc1 = c_; ws1 = -s_;
                }
                rot2col(z12, z22, z32, z13, z23, z33, wc2, ws2);   // rotcf(2,3)
                rot2col(z11, z21, z31, z12, z22, z32, wc1, ws1);   // rotcf(1,2)
                d1 = fs(d1, p); e1 = g;
            }
        } else {
            // QR iteration
            for (;;) {
                int mq = lend;
                if (l != lend) {
                    for (mq = l; mq >= lend + 1; --mq) {
                        float tst = fm(RE(mq - 1), RE(mq - 1));
                        if (tst <= fa(fm(fm(eps2, fabsf(RD(mq))), fabsf(RD(mq - 1))), safmin)) break;
                    }
                }
                if (mq > lend) WRE(mq - 1, 0.0f);
                float p = RD(l);
                if (mq == l) { l -= 1; if (l >= lend) continue; break; }
                if (mq == l - 1) {
                    float rt1, rt2, cc, ss;
                    if (l == 2) {
                        slaev2_(d1, e1, d2, rt1, rt2, cc, ss);
                        rot2col(z11, z21, z31, z12, z22, z32, cc, ss);
                        d1 = rt1; d2 = rt2; e1 = 0.0f;
                    } else {  // l == 3
                        slaev2_(d2, e2, d3, rt1, rt2, cc, ss);
                        rot2col(z12, z22, z32, z13, z23, z33, cc, ss);
                        d2 = rt1; d3 = rt2; e2 = 0.0f;
                    }
                    l -= 2; if (l >= lend) continue; break;
                }
                if (jtot == nmaxit) break;
                jtot++;
                // sweep: reachable only with l==3, mq==1
                float g = fs(d2, p) / fm(2.0f, e2);
                float r = slapy2_(g, 1.0f);
                g = fa(fs(d1, p), e2 / fa(g, fsignf(r, g)));
                float s_ = 1.0f, c_ = 1.0f; p = 0.0f;
                {   // i = 1 (== mq: no E(i-1) store)
                    float f = fm(s_, e1), b = fm(c_, e1);
                    slartg_(g, f, c_, s_, r);
                    g = fs(d1, p);
                    r = fa(fm(fs(d2, g), s_), fm(fm(2.0f, c_), b));
                    p = fm(s_, r);
                    d1 = fa(g, p);
                    g = fs(fm(c_, r), b);
                    wc1 = c_; ws1 = s_;       // QR stores +S
                }
                {   // i = 2: E(1) = r
                    float f = fm(s_, e2), b = fm(c_, e2);
                    slartg_(g, f, c_, s_, r);
                    e1 = r;
                    g = fs(d2, p);
                    r = fa(fm(fs(d3, g), s_), fm(fm(2.0f, c_), b));
                    p = fm(s_, r);
                    d2 = fa(g, p);
                    g = fs(fm(c_, r), b);
                    wc2 = c_; ws2 = s_;
                }
                rot2col(z11, z21, z31, z12, z22, z32, wc1, ws1);   // rotcf(1,2)
                rot2col(z12, z22, z32, z13, z23, z33, wc2, ws2);   // rotcf(2,3)
                d3 = fs(d3, p); e2 = g;
            }
        }
    }
    // ascending selection sort with column swaps (ssteqr tail)
    for (int ii = 2; ii <= 3; ++ii) {
        int i = ii - 1, kk = i; float p = RD(i);
        for (int j = ii; j <= 3; ++j) { float dj = RD(j); if (dj < p) { kk = j; p = dj; } }
        if (kk != i) {
            WRD(kk, RD(i)); WRD(i, p);
            if (i == 1 && kk == 2)      { SWAPC(z11, z12); SWAPC(z21, z22); SWAPC(z31, z32); }
            else if (i == 1 && kk == 3) { SWAPC(z11, z13); SWAPC(z21, z23); SWAPC(z31, z33); }
            else                        { SWAPC(z12, z13); SWAPC(z22, z23); SWAPC(z32, z33); }
        }
    }
    // sormtr: Z := H1 * Z (rows 2..3), slarf/sger op order
    if (tau != 0.0f) {
        float ss, t;
        ss = fa(z21, fm(v3, z31)); t = fm(tau, ss); z21 = fs(z21, t); z31 = fs(z31, fm(t, v3));
        ss = fa(z22, fm(v3, z32)); t = fm(tau, ss); z22 = fs(z22, t); z32 = fs(z32, fm(t, v3));
        ss = fa(z23, fm(v3, z33)); t = fm(tau, ss); z23 = fs(z23, t); z33 = fs(z33, fm(t, v3));
    }
    v1o = z11; v2o = z21; v3o = z31;
}

// ---------------- JAX threefry2x32 (key(42) noise reproduction)
__device__ void threefry2x32_(unsigned k0, unsigned k1, unsigned c0, unsigned c1,
                              unsigned& o0, unsigned& o1) {
    const unsigned rot[8] = {13u, 15u, 26u, 6u, 17u, 29u, 16u, 24u};
    unsigned ks[3] = {k0, k1, k0 ^ k1 ^ 0x1BD11BDAu};
    unsigned x0 = c0 + k0, x1 = c1 + k1;
    for (int blk = 0; blk < 5; ++blk) {
        const unsigned* r = &rot[(blk & 1) * 4];
        for (int i = 0; i < 4; ++i) {
            x0 += x1;
            x1 = (x1 << r[i]) | (x1 >> (32 - r[i]));
            x1 ^= x0;
        }
        x0 += ks[(blk + 1) % 3];
        x1 += ks[(blk + 2) % 3] + (unsigned)(blk + 1);
    }
    o0 = x0; o1 = x1;
}

// noise[j] = (uniform(key(42),(100,3))[j,j] - 0.5) * 1e-8 ; flat idx m = 4*j
__device__ float noise_diag_(int j) {
    unsigned m = (unsigned)(4 * j);
    unsigned o0, o1;
    threefry2x32_(0u, 42u, m, 150u + m, o0, o1);  // m<150 -> first-half output
    unsigned bits = (o0 >> 9) | 0x3f800000u;
    float u = fs(__uint_as_float(bits), 1.0f);    // [0,1)
    return fm(fs(u, 0.5f), 1e-8f);
}

__device__ __forceinline__ float angf(float ax, float ay, float az,
                                      float bx, float by, float bz) {
    float cx = ay * bz - az * by;
    float cy = az * bx - ax * bz;
    float cz = ax * by - ay * bx;
    float cn = sqrtf(cx * cx + cy * cy + cz * cz);
    float d  = ax * bx + ay * by + az * bz;
    return atan2f(cn, d);
}

// ---------------------------------------------------------------- grid build

__global__ void k_prep(const float* __restrict__ pts, float4* __restrict__ pos4,
                       int* __restrict__ pcell, int* __restrict__ hist, int n) {
    int i = blockIdx.x * blockDim.x + threadIdx.x;
    if (i < n) {
        float x = pts[i * 3], y = pts[i * 3 + 1], z = pts[i * 3 + 2];
        float sq = fa(fa(fm(x, x), fm(y, y)), fm(z, z));
        pos4[i] = make_float4(x, y, z, sq);
        int cx = (int)(x * 8.0f); cx = cx < 0 ? 0 : (cx > GRD - 1 ? GRD - 1 : cx);
        int cy = (int)(y * 8.0f); cy = cy < 0 ? 0 : (cy > GRD - 1 ? GRD - 1 : cy);
        int cz = (int)(z * 8.0f); cz = cz < 0 ? 0 : (cz > GRD - 1 ? GRD - 1 : cz);
        int cid = (cz * GRD + cy) * GRD + cx;
        pcell[i] = cid;
        atomicAdd(&hist[cid], 1);
    }
}

// single block, NCELL threads: exclusive scan of hist -> start[0..NCELL], cursor copy
__global__ __launch_bounds__(NCELL) void k_scan(const int* __restrict__ hist,
                                                int* __restrict__ start,
                                                int* __restrict__ cursor) {
    __shared__ int s[NCELL];
    int t = threadIdx.x;
    int v = hist[t];
    s[t] = v;
    __syncthreads();
    for (int off = 1; off < NCELL; off <<= 1) {
        int x = (t >= off) ? s[t - off] : 0;
        __syncthreads();
        s[t] += x;
        __syncthreads();
    }
    int ex = s[t] - v;
    start[t] = ex;
    cursor[t] = ex;
    if (t == NCELL - 1) start[NCELL] = s[t];
}

__global__ void k_scatter(const int* __restrict__ pcell, int* __restrict__ cursor,
                          int* __restrict__ order, int n) {
    int i = blockIdx.x * blockDim.x + threadIdx.x;
    if (i < n) {
        int slot = atomicAdd(&cursor[pcell[i]], 1);
        order[slot] = i;
    }
}

// ---------------------------------------------------------------- grid KNN
#define KEY_WORST 0xC0001FFFFFFFFFFFull
#define CBUF 128

__global__ __launch_bounds__(256) void k_knn(const float4* __restrict__ pos4,
                                             const int* __restrict__ order,
                                             const int* __restrict__ cstart,
                                             int* __restrict__ cols, int n) {
    __shared__ unsigned long long sbuf[4][CBUF];
    __shared__ int scnt[4];

    int lane = threadIdx.x & 63;
    int wv = threadIdx.x >> 6;
    int io = blockIdx.x * 4 + wv;
    if (io >= n) return;   // no block-wide barriers below: per-wave exit is safe

    float4 P = pos4[io];
    int cx = (int)(P.x * 8.0f); cx = cx < 0 ? 0 : (cx > GRD - 1 ? GRD - 1 : cx);
    int cy = (int)(P.y * 8.0f); cy = cy < 0 ? 0 : (cy > GRD - 1 ? GRD - 1 : cy);
    int cz = (int)(P.z * 8.0f); cz = cz < 0 ? 0 : (cz > GRD - 1 ? GRD - 1 : cz);

    unsigned T = 0xFFFFFFFFu;
    int xlo = 0, xhi = 0, ylo = 0, yhi = 0, zlo = 0, zhi = 0;

    for (int r = 1; r < 16; ++r) {
        xlo = cx - r; if (xlo < 0) xlo = 0;
        xhi = cx + r; if (xhi > GRD - 1) xhi = GRD - 1;
        ylo = cy - r; if (ylo < 0) ylo = 0;
        yhi = cy + r; if (yhi > GRD - 1) yhi = GRD - 1;
        zlo = cz - r; if (zlo < 0) zlo = 0;
        zhi = cz + r; if (zhi > GRD - 1) zhi = GRD - 1;

        // ---- pass 1: per-lane top-2 raw-bit d2 over the cell block
        unsigned b0 = 0xFFFFFFFFu, b1 = 0xFFFFFFFFu;
        for (int zz = zlo; zz <= zhi; ++zz)
            for (int yy = ylo; yy <= yhi; ++yy) {
                int rowb = (zz * GRD + yy) * GRD;   // x-cells contiguous
                int jb = cstart[rowb + xlo];
                int je = cstart[rowb + xhi + 1];
                for (int t = jb + lane; t < je; t += 64) {
                    int j = order[t];
                    float4 Q = pos4[j];
                    float g = fm(P.x, Q.x);
                    g = fmaf(P.y, Q.y, g);
                    g = fmaf(P.z, Q.z, g);
                    float d2 = fs(fa(P.w, Q.w), fm(2.0f, g));
                    unsigned u = __float_as_uint(d2);
                    u = (j == io) ? 0xFFFFFFFFu : u;
                    unsigned lo = umin32(b0, u);
                    unsigned hi = umax32(b0, u);
                    b0 = lo;
                    b1 = umin32(b1, hi);
                }
            }

        // ---- 13th smallest of per-lane top-2 union: upper bound on true 13th
        {
            unsigned h0 = b0, h1 = b1;
            T = 0xFFFFFFFFu;
            for (int rr = 0; rr < KNB + 1; ++rr) {
                unsigned mn = h0;
#pragma unroll
                for (int off = 32; off >= 1; off >>= 1) {
                    unsigned o = (unsigned)__shfl_xor((int)mn, off, 64);
                    mn = umin32(mn, o);
                }
                unsigned long long bl = __ballot(h0 == mn);
                int first = __ffsll(bl) - 1;
                if (lane == first) { h0 = h1; h1 = 0xFFFFFFFFu; }
                T = mn;
            }
        }

        // ---- sufficiency: all true top-12 inside the searched block?
        bool cover = (xlo == 0) && (xhi == GRD - 1) && (ylo == 0) && (yhi == GRD - 1)
                  && (zlo == 0) && (zhi == GRD - 1);
        if (cover) break;
        if (T != 0xFFFFFFFFu) {
            // distance from P to nearest in-cube face of the searched block
            float gmin = 1e30f;
            if (xlo > 0)       gmin = fminf(gmin, fs(P.x, (float)xlo * 0.125f));
            if (xhi < GRD - 1) gmin = fminf(gmin, fs((float)(xhi + 1) * 0.125f, P.x));
            if (ylo > 0)       gmin = fminf(gmin, fs(P.y, (float)ylo * 0.125f));
            if (yhi < GRD - 1) gmin = fminf(gmin, fs((float)(yhi + 1) * 0.125f, P.y));
            if (zlo > 0)       gmin = fminf(gmin, fs(P.z, (float)zlo * 0.125f));
            if (zhi < GRD - 1) gmin = fminf(gmin, fs((float)(zhi + 1) * 0.125f, P.z));
            float g2 = fm(fm(gmin, gmin), 0.9995f);   // margin >> f32 rounding
            if (__uint_as_float(T) <= g2) break;
        }
        // else: expand ring (rare: anomalously sparse neighborhoods)
    }

    // ---- pass 2: compact candidates with raw bits <= T into the wave buffer
    if (lane == 0) scnt[wv] = 0;
    __builtin_amdgcn_wave_barrier();
    for (int zz = zlo; zz <= zhi; ++zz)
        for (int yy = ylo; yy <= yhi; ++yy) {
            int rowb = (zz * GRD + yy) * GRD;
            int jb = cstart[rowb + xlo];
            int je = cstart[rowb + xhi + 1];
            for (int t = jb + lane; t < je; t += 64) {
                int j = order[t];
                float4 Q = pos4[j];
                float g = fm(P.x, Q.x);
                g = fmaf(P.y, Q.y, g);
                g = fmaf(P.z, Q.z, g);
                float d2 = fs(fa(P.w, Q.w), fm(2.0f, g));
                unsigned u = __float_as_uint(d2);
                bool c = (u <= T) && (j != io);
                unsigned long long bl = __ballot(c);
                if (bl) {
                    int leader = __ffsll(bl) - 1;
                    int base = 0;
                    if (lane == leader)
                        base = atomicAdd(&scnt[wv], (int)__popcll(bl));
                    base = __shfl(base, leader, 64);
                    if (c) {
                        int pos = base + (int)__popcll(bl & ((1ull << lane) - 1ull));
                        unsigned us = u ^ (unsigned)(((int)u >> 31) | 0x80000000);
                        unsigned long long kb = (((unsigned long long)us << 13) | (unsigned)j)
                                                | 0xC000000000000000ull;
                        if (pos < CBUF) sbuf[wv][pos] = kb;
                    }
                }
            }
        }
    __builtin_amdgcn_wave_barrier();
    int cnt = scnt[wv];
    if (cnt > CBUF) cnt = CBUF;

    // ---- exact top-12 from buffer (packed keys as negative doubles: fmax = min-key)
    double k0 = __longlong_as_double((long long)KEY_WORST);
    double k1 = __longlong_as_double((long long)KEY_WORST);
    if (lane < cnt) k0 = __longlong_as_double((long long)sbuf[wv][lane]);
    if (lane + 64 < cnt) k1 = __longlong_as_double((long long)sbuf[wv][lane + 64]);
    double mykey = __longlong_as_double((long long)KEY_WORST);
    for (int rr = 0; rr < KNB; ++rr) {
        double mx = fmax(k0, k1);
#pragma unroll
        for (int off = 32; off >= 1; off >>= 1)
            mx = fmax(mx, __shfl_xor(mx, off, 64));
        if (k0 == mx) k0 = __longlong_as_double((long long)KEY_WORST);
        else if (k1 == mx) k1 = __longlong_as_double((long long)KEY_WORST);
        if (lane == rr) mykey = mx;
    }
    if (lane < KNB) {
        unsigned long long bits = (unsigned long long)__double_as_longlong(mykey);
        unsigned j = (unsigned)(bits & 0x1FFFu);
        unsigned u = (unsigned)((bits >> 13) & 0xFFFFFFFFull);
        unsigned ob = (u & 0x80000000u) ? (u ^ 0x80000000u) : ~u;
        float d2 = __uint_as_float(ob);
        cols[io * KNB + lane] = (d2 <= 0.25f) ? (int)j : io;
    }
}

// ---------------------------------------------------------------- normals
__global__ __launch_bounds__(64) void k_normals(const float4* __restrict__ pos4,
                                                const int* __restrict__ cols,
                                                float4* __restrict__ nrm4,
                                                float* __restrict__ out, int n) {
    int i = blockIdx.x * blockDim.x + threadIdx.x;
    if (i >= n) return;

    float qx[KNB], qy[KNB], qz[KNB];
#pragma unroll
    for (int k = 0; k < KNB; ++k) {
        float4 q = pos4[cols[i * KNB + k]];
        qx[k] = q.x; qy[k] = q.y; qz[k] = q.z;
    }
    // mean: f32 sequential over k
    float sx = qx[0], sy = qy[0], sz = qz[0];
#pragma unroll
    for (int k = 1; k < KNB; ++k) { sx = fa(sx, qx[k]); sy = fa(sy, qy[k]); sz = fa(sz, qz[k]); }
    float mx = sx / 12.0f, my = sy / 12.0f, mz = sz / 12.0f;
    // cov: f32 sequential over k (np.einsum order)
    float c00 = 0, c10 = 0, c20 = 0, c11 = 0, c21 = 0, c22 = 0;
#pragma unroll
    for (int k = 0; k < KNB; ++k) {
        float dx = fs(qx[k], mx), dy = fs(qy[k], my), dz = fs(qz[k], mz);
        c00 = fa(c00, fm(dx, dx));
        c10 = fa(c10, fm(dy, dx));
        c20 = fa(c20, fm(dz, dx));
        c11 = fa(c11, fm(dy, dy));
        c21 = fa(c21, fm(dz, dy));
        c22 = fa(c22, fm(dz, dz));
    }
    c00 = c00 / 12.0f; c10 = c10 / 12.0f; c20 = c20 / 12.0f;
    c11 = c11 / 12.0f; c21 = c21 / 12.0f; c22 = c22 / 12.0f;
    // + jnp.diag(noise): np eigh reads lower, A[i][j] += v[j]
    float v0 = noise_diag_(0), v1 = noise_diag_(1), v2 = noise_diag_(2);
    float a00 = fa(c00, v0), a10 = fa(c10, v0), a20 = fa(c20, v0);
    float a11 = fa(c11, v1), a21 = fa(c21, v1), a22 = fa(c22, v2);
    float e1, e2, e3;
    eig3_smallest_reg(a00, a10, a20, a11, a21, a22, e1, e2, e3);
    nrm4[i] = make_float4(e1, e2, e3, 0.0f);
    out[i]         = e1;
    out[n + i]     = e2;
    out[2 * n + i] = e3;
}

// ---------------------------------------------------------------- MLP chain
// 24 threads/point arranged so the hidden-half split is WAVE-UNIFORM:
// waves 0-2 <-> hf=0, waves 3-5 <-> hf=1 (hf = tid/192, readfirstlane'd to
// SGPR). Weight indices in the l-MLPs are then wave-uniform -> compiler emits
// scalar s_load (SMEM) weight reads folded into v_fmac, as in the efficient
// R2 codegen. R4's lane-interleaved hf made weight loads divergent vector
// loads (~200cy each) -> VALUBusy 20%, 93 us.
// g-MLPs stay lane-distributed (divergent but only ~4% of MACs).
// Hidden loops NOT unrolled (R3 lesson: full unroll -> 40MB scratch spills).

struct WPtrs { const float* p[28]; };

// half of an l-MLP: this thread computes hidden units [hf*NH/2, (hf+1)*NH/2)
template <int NI, int NH, int NO>
__device__ __forceinline__ void mlp_half(const float* __restrict__ w1, const float* __restrict__ b1,
                                         const float* __restrict__ w2, const float* __restrict__ b2,
                                         const float* in, float* out, int hf) {
#pragma unroll
    for (int o = 0; o < NO; ++o) out[o] = hf ? 0.0f : b2[o];
    const int HH = NH / 2;
    int h0 = hf * HH;
    for (int hi = 0; hi < HH; ++hi) {   // no unroll: avoids VGPR spill
        int h = h0 + hi;                // wave-uniform -> scalar weight loads
        float hh = b1[h];
#pragma unroll
        for (int ii = 0; ii < NI; ++ii) hh = fmaf(in[ii], w1[ii * NH + h], hh);
        hh = fmaxf(hh, 0.0f);
#pragma unroll
        for (int o = 0; o < NO; ++o) out[o] = fmaf(hh, w2[h * NO + o], out[o]);
    }
}

// g-MLP (NH=32) partial: thread q handles h=q, plus h=24+q when q<8.
template <int NI, int NO>
__device__ __forceinline__ void gmlp_part(const float* __restrict__ w1, const float* __restrict__ b1,
                                          const float* __restrict__ w2, const float* __restrict__ b2,
                                          const float* in, float* pout, int q) {
#pragma unroll
    for (int o = 0; o < NO; ++o) pout[o] = (q == 0) ? b2[o] : 0.0f;
    {
        float hh = b1[q];
#pragma unroll
        for (int ii = 0; ii < NI; ++ii) hh = fmaf(in[ii], w1[ii * 32 + q], hh);
        hh = fmaxf(hh, 0.0f);
#pragma unroll
        for (int o = 0; o < NO; ++o) pout[o] = fmaf(hh, w2[q * NO + o], pout[o]);
    }
    if (q < 8) {
        int h = 24 + q;
        float hh = b1[h];
#pragma unroll
        for (int ii = 0; ii < NI; ++ii) hh = fmaf(in[ii], w1[ii * 32 + h], hh);
        hh = fmaxf(hh, 0.0f);
#pragma unroll
        for (int o = 0; o < NO; ++o) pout[o] = fmaf(hh, w2[h * NO + o], pout[o]);
    }
}

#define SCR(pp, qq, oo) s_scr[((pp) * 24 + (qq)) * 17 + (oo)]
#define SM(pp, oo)      s_m[(pp) * 17 + (oo)]
#define GFV(pp, oo)     s_g[(pp) * 13 + (oo)]
#define SLG(pp, kk)     s_log[(pp) * 13 + (kk)]

__global__ __launch_bounds__(384) void k_mlp(const float4* __restrict__ pos4,
                                             const int* __restrict__ cols,
                                             const float4* __restrict__ nrm4,
                                             WPtrs wp, float* __restrict__ out, int n) {
    __shared__ float s_scr[16 * 24 * 17];   // partial buffers (l-halves / g-lanes)
    __shared__ float s_m[16 * 17];          // per-point means
    __shared__ float s_g[16 * 13];          // g-MLP outputs
    __shared__ float s_log[16 * 13];        // logits
    __shared__ float s_red[16 * 2];         // softmax max/sum

    int t = threadIdx.x;
    int tm = t % 192;                       // waves 0-2: tm==t; waves 3-5: t-192
    int p = tm / 12, k = tm - p * 12;
    int hf = __builtin_amdgcn_readfirstlane(t / 192);   // wave-uniform SGPR
    int q = hf * 12 + k;
    int nn = blockIdx.x * 16 + p;
    bool act = (nn < n);

    float cx = 0, cy = 0, cz = 0, nrx = 0, nry = 0, nrz = 0;
    float xr[16];

    // ---- stage A: edge features + l1 (half)
    if (act) {
        int col = cols[nn * 12 + k];
        float4 P = pos4[nn], Q = pos4[col];
        cx = Q.x - P.x; cy = Q.y - P.y; cz = Q.z - P.z;
        float dist = sqrtf(cx * cx + cy * cy + cz * cz);
        float4 NR = nrm4[nn], NC = nrm4[col];
        nrx = NR.x; nry = NR.y; nrz = NR.z;
        float a1 = angf(nrx, nry, nrz, cx, cy, cz);
        float a2 = angf(NC.x, NC.y, NC.z, cx, cy, cz);
        float a3 = angf(nrx, nry, nrz, NC.x, NC.y, NC.z);
        float in7[7] = {cx, cy, cz, dist, a1, a2, a3};
        float px[16];
        mlp_half<7, 32, 16>(wp.p[0], wp.p[1], wp.p[2], wp.p[3], in7, px, hf);
#pragma unroll
        for (int o = 0; o < 16; ++o) SCR(p, q, o) = px[o];
    }
    __syncthreads();
    if (act) {
#pragma unroll
        for (int o = 0; o < 16; ++o) xr[o] = SCR(p, k, o) + SCR(p, 12 + k, o);
    }
    __syncthreads();

    // ---- stage B: mean + g1 (lane-parallel; mean from partial rows, same
    //      summation order as before: s += (half0 + half1) per edge)
    if (act && q < 16) {
        float s = 0.0f;
        for (int kk = 0; kk < 12; ++kk) s += SCR(p, kk, q) + SCR(p, 12 + kk, q);
        SM(p, q) = s / 12.0f;
    }
    __syncthreads();
    if (act) {
        float gin[19];
#pragma unroll
        for (int ii = 0; ii < 16; ++ii) gin[ii] = SM(p, ii);
        gin[16] = nrx; gin[17] = nry; gin[18] = nrz;
        float pg[8];
        gmlp_part<19, 8>(wp.p[4], wp.p[5], wp.p[6], wp.p[7], gin, pg, q);
#pragma unroll
        for (int o = 0; o < 8; ++o) SCR(p, q, o) = pg[o];
    }
    __syncthreads();
    if (act && q < 8) {
        float s = 0.0f;
        for (int j = 0; j < 24; ++j) s += SCR(p, j, q);
        GFV(p, q) = s;
    }
    __syncthreads();

    // ---- stage C: l2 (half)
    if (act) {
        float in24[24];
#pragma unroll
        for (int o = 0; o < 16; ++o) in24[o] = xr[o];
#pragma unroll
        for (int o = 0; o < 8; ++o) in24[16 + o] = GFV(p, o);
        float px[16];
        mlp_half<24, 32, 16>(wp.p[8], wp.p[9], wp.p[10], wp.p[11], in24, px, hf);
#pragma unroll
        for (int o = 0; o < 16; ++o) SCR(p, q, o) = px[o];
    }
    __syncthreads();
    if (act) {
#pragma unroll
        for (int o = 0; o < 16; ++o) xr[o] = SCR(p, k, o) + SCR(p, 12 + k, o);
    }
    __syncthreads();

    // ---- stage D: mean + g2
    if (act && q < 16) {
        float s = 0.0f;
        for (int kk = 0; kk < 12; ++kk) s += SCR(p, kk, q) + SCR(p, 12 + kk, q);
        SM(p, q) = s / 12.0f;
    }
    __syncthreads();
    if (act) {
        float gin[16];
#pragma unroll
        for (int ii = 0; ii < 16; ++ii) gin[ii] = SM(p, ii);
        float pg[8];
        gmlp_part<16, 8>(wp.p[12], wp.p[13], wp.p[14], wp.p[15], gin, pg, q);
#pragma unroll
        for (int o = 0; o < 8; ++o) SCR(p, q, o) = pg[o];
    }
    __syncthreads();
    if (act && q < 8) {
        float s = 0.0f;
        for (int j = 0; j < 24; ++j) s += SCR(p, j, q);
        GFV(p, q) = s;
    }
    __syncthreads();

    // ---- stage E: l3 (half)
    if (act) {
        float in24[24];
#pragma unroll
        for (int o = 0; o < 16; ++o) in24[o] = xr[o];
#pragma unroll
        for (int o = 0; o < 8; ++o) in24[16 + o] = GFV(p, o);
        float px[16];
        mlp_half<24, 32, 16>(wp.p[16], wp.p[17], wp.p[18], wp.p[19], in24, px, hf);
#pragma unroll
        for (int o = 0; o < 16; ++o) SCR(p, q, o) = px[o];
    }
    __syncthreads();
    if (act) {
#pragma unroll
        for (int o = 0; o < 16; ++o) xr[o] = SCR(p, k, o) + SCR(p, 12 + k, o);
    }
    __syncthreads();

    // ---- stage F: mean + g3 (12 outputs)
    if (act && q < 16) {
        float s = 0.0f;
        for (int kk = 0; kk < 12; ++kk) s += SCR(p, kk, q) + SCR(p, 12 + kk, q);
        SM(p, q) = s / 12.0f;
    }
    __syncthreads();
    if (act) {
        float gin[16];
#pragma unroll
        for (int ii = 0; ii < 16; ++ii) gin[ii] = SM(p, ii);
        float pg[12];
        gmlp_part<16, 12>(wp.p[20], wp.p[21], wp.p[22], wp.p[23], gin, pg, q);
#pragma unroll
        for (int o = 0; o < 12; ++o) SCR(p, q, o) = pg[o];
    }
    __syncthreads();
    if (act && q < 12) {
        float s = 0.0f;
        for (int j = 0; j < 24; ++j) s += SCR(p, j, q);
        GFV(p, q) = s;
    }
    __syncthreads();

    // ---- stage G: quat->mat (computed redundantly per thread) + l4 (half)
    if (act) {
        float g0 = GFV(p, 0), g1v = GFV(p, 1), g2v = GFV(p, 2), g3v = GFV(p, 3);
        float qn = sqrtf(g0 * g0 + g1v * g1v + g2v * g2v + g3v * g3v) + 1e-8f;
        float qw = g0 / qn, qxx = g1v / qn, qyy = g2v / qn, qzz = g3v / qn;
        float m0 = 1.0f - 2.0f * (qyy * qyy + qzz * qzz);
        float m1 = 2.0f * (qxx * qyy - qzz * qw);
        float m2 = 2.0f * (qxx * qzz + qyy * qw);
        float m3 = 2.0f * (qxx * qyy + qzz * qw);
        float m4 = 1.0f - 2.0f * (qxx * qxx + qzz * qzz);
        float m5 = 2.0f * (qyy * qzz - qxx * qw);
        float m6 = 2.0f * (qxx * qzz - qyy * qw);
        float m7 = 2.0f * (qyy * qzz + qxx * qw);
        float m8 = 1.0f - 2.0f * (qxx * qxx + qyy * qyy);
        float r0 = m0 * cx + m1 * cy + m2 * cz;
        float r1 = m3 * cx + m4 * cy + m5 * cz;
        float r2 = m6 * cx + m7 * cy + m8 * cz;
        float in27[27];
#pragma unroll
        for (int o = 0; o < 16; ++o) in27[o] = xr[o];
#pragma unroll
        for (int o = 0; o < 8; ++o) in27[16 + o] = GFV(p, 4 + o);
        in27[24] = r0; in27[25] = r1; in27[26] = r2;
        float plg[1];
        mlp_half<27, 64, 1>(wp.p[24], wp.p[25], wp.p[26], wp.p[27], in27, plg, hf);
        SCR(p, q, 0) = plg[0];
    }
    __syncthreads();
    if (act && hf == 0) SLG(p, k) = SCR(p, k, 0) + SCR(p, 12 + k, 0);
    __syncthreads();

    // ---- stage H: softmax over the 12 edges (same op order as reference)
    if (act && q == 0) {
        float mx = SLG(p, 0);
        for (int kk = 1; kk < 12; ++kk) mx = fmaxf(mx, SLG(p, kk));
        float se = 0;
        for (int kk = 0; kk < 12; ++kk) se += expf(SLG(p, kk) - mx);
        s_red[p * 2] = mx; s_red[p * 2 + 1] = se;
    }
    __syncthreads();
    if (act && hf == 0) {
        float v = expf(SLG(p, k) - s_red[p * 2]) / s_red[p * 2 + 1];
        out[3 * n + k * n + nn] = v;
    }
}

// ---------------------------------------------------------------- launch

extern "C" void kernel_launch(void* const* d_in, const int* in_sizes, int n_in,
                              void* d_out, int out_size, void* d_ws, size_t ws_size,
                              hipStream_t stream) {
    const float* pts = (const float*)d_in[0];
    int n = in_sizes[0] / 3;

    char* ws = (char*)d_ws;
    float4* pos4  = (float4*)ws;                            // n*16 B
    int*    cols  = (int*)(ws + (size_t)n * 16);            // n*48 B
    float4* nrm4  = (float4*)(ws + (size_t)n * 64);         // n*16 B
    int*    pcell = (int*)(ws + (size_t)n * 80);            // n*4 B
    int*    order = (int*)(ws + (size_t)n * 84);            // n*4 B
    int*    hist  = (int*)(ws + (size_t)n * 88);            // NCELL ints
    int*    start = hist + NCELL;                           // NCELL+1 ints
    int*    cursor = start + NCELL + 1;                     // NCELL ints
    float*  out = (float*)d_out;

    WPtrs wp;
    for (int a = 0; a < 28; ++a) wp.p[a] = (const float*)d_in[a + 1];

    hipMemsetAsync(hist, 0, NCELL * sizeof(int), stream);
    k_prep<<<(n + 255) / 256, 256, 0, stream>>>(pts, pos4, pcell, hist, n);
    k_scan<<<1, NCELL, 0, stream>>>(hist, start, cursor);
    k_scatter<<<(n + 255) / 256, 256, 0, stream>>>(pcell, cursor, order, n);
    k_knn<<<(n + 3) / 4, 256, 0, stream>>>(pos4, order, start, cols, n);
    k_normals<<<(n + 63) / 64, 64, 0, stream>>>(pos4, cols, nrm4, out, n);
    // 24 threads/point: waves 0-2 = hidden-half 0, waves 3-5 = hidden-half 1
    k_mlp<<<(n + 15) / 16, 384, 0, stream>>>(pos4, cols, nrm4, wp, out, n);
}